// Round 6
// baseline (1416.878 us; speedup 1.0000x reference)
//
#include <hip/hip_runtime.h>
#include <hip/hip_bf16.h>
#include <math.h>

#define B_ 128
#define T_ 32
#define IN_ 512
#define H_ 512
#define M_ 16
#define WC_ 20
#define R_ 4
#define RW_ 80
#define NNIN_ 592
#define IFACE_ 163
#define IFP_ 176
#define K1P_ 1120
#define K2P_ 1024
#define KOP_ 608
#define CLIP_ 20.0f
#define EPS_ 1e-6f
#define DELTA_ 5e-6f
#define NBLK_ 1536
#define SCOPE_ __HIP_MEMORY_SCOPE_AGENT

typedef __bf16 bf16x8 __attribute__((ext_vector_type(8)));
typedef float f32x4 __attribute__((ext_vector_type(4)));

__device__ __forceinline__ float sigmoidf_(float x) { return 1.0f / (1.0f + __expf(-x)); }
__device__ __forceinline__ float tanhf_(float x) {
    float e = __expf(-2.f * fabsf(x));
    float t = (1.f - e) / (1.f + e);
    return copysignf(t, x);
}
__device__ __forceinline__ float softplusf_(float x) {
    return fmaxf(x, 0.0f) + log1pf(__expf(-fabsf(x)));
}
__device__ __forceinline__ void split2(float v, __bf16* hp, __bf16* lp) {
    __bf16 h = (__bf16)v;
    *hp = h;
    *lp = (__bf16)(v - (float)h);
}

// ---------------------------------------------------------------------------
// Coherent (agent-scope, L2-bypassing) access helpers. All data handed off
// between DIFFERENT blocks across slot barriers goes through these; they hit
// the L3 coherence point, so no L2 writeback/invalidate is ever needed.
// ---------------------------------------------------------------------------
__device__ __forceinline__ bf16x8 ldA(const __bf16* p) {
    union { unsigned long long q[2]; bf16x8 v; } u;
    unsigned long long* q = (unsigned long long*)p;
    u.q[0] = __hip_atomic_load(q,     __ATOMIC_RELAXED, SCOPE_);
    u.q[1] = __hip_atomic_load(q + 1, __ATOMIC_RELAXED, SCOPE_);
    return u.v;
}
__device__ __forceinline__ unsigned pk(__bf16 a, __bf16 b) {
    union { __bf16 h[2]; unsigned u; } x;
    x.h[0] = a; x.h[1] = b;
    return x.u;
}
__device__ __forceinline__ void st32(__bf16* p, unsigned v) {
    __hip_atomic_store((unsigned*)p, v, __ATOMIC_RELAXED, SCOPE_);
}
__device__ __forceinline__ void st32f(float* p, float v) {
    __hip_atomic_store((unsigned*)p, __float_as_uint(v), __ATOMIC_RELAXED, SCOPE_);
}
__device__ __forceinline__ float ld32f(const float* p) {
    return __uint_as_float(__hip_atomic_load((unsigned*)p, __ATOMIC_RELAXED, SCOPE_));
}

// ---------------------------------------------------------------------------
// Parameter block. LSTM/out weights: single bf16 limb. iface weights: 2-limb.
// ---------------------------------------------------------------------------
struct P {
    const float *x, *bih0, *bhh0, *bih1, *bhh1, *bif0, *bif1, *bout;
    float* out;
    __bf16 *a10h[4], *a10l[4];   // [x | 0 | h00], stride K1P
    __bf16 *a11h[4], *a11l[4];   // [out0 | rv0 | h10], stride K1P
    __bf16 *a20h[4], *a20l[4];   // [h0A | h01], stride K2P
    __bf16 *a21h[4], *a21l[4];   // [h1A | h11], stride K2P
    __bf16 *yh[4],  *yl[4];      // [out1 | rv1 | pad], stride KOP
    float *c00, *c01, *c10, *c11;
    float *mem0, *link0, *prec0, *rw0, *ww0, *us0;
    float *mem1, *link1, *prec1, *rw1, *ww1, *us1;
    __bf16 *w10, *w20, *w11, *w21, *wo;
    __bf16 *wif0h, *wif0l, *wif1h, *wif1l;   // [IFP_ x 512]
    float *S0[2], *S1[2];                    // [B_ x IFP_] activated iface
    unsigned *bar;                            // barrier state (zeroed)
};

// ---------------------------------------------------------------------------
// Fence-free grid barrier. Co-residency: 1536 blocks = 6/CU exactly, enforced
// by launch_bounds(256,6) — empirically proven live in the R4 run.
// Monotonic counters (no resets): shard i at bar[i*32] (48 blocks each),
// root at bar[1024], per-shard generation words at bar[1056 + i*32].
// No cache ops: all cross-block data uses agent-scope (L3) accesses, and
// __syncthreads' vmcnt drain guarantees those stores are acked before arrive.
// ---------------------------------------------------------------------------
__device__ __forceinline__ void grid_barrier(unsigned* bar, int blk, int tid, unsigned g)
{
    __syncthreads();
    if (tid == 0) {
        const int sh = blk & 31;
        unsigned a = __hip_atomic_fetch_add(&bar[sh * 32], 1u,
                        __ATOMIC_RELAXED, SCOPE_);
        if (a == g * 48u + 47u) {
            unsigned r = __hip_atomic_fetch_add(&bar[1024], 1u,
                            __ATOMIC_RELAXED, SCOPE_);
            if (r == g * 32u + 31u) {
                #pragma unroll
                for (int s2 = 0; s2 < 32; ++s2)
                    __hip_atomic_store(&bar[1056 + s2 * 32], g + 1u,
                        __ATOMIC_RELAXED, SCOPE_);
            }
        }
        long long spins = 0;
        while (__hip_atomic_load(&bar[1056 + sh * 32], __ATOMIC_RELAXED,
                                 SCOPE_) <= g) {
            __builtin_amdgcn_s_sleep(4);
            if (++spins > (1LL << 18)) break;   // bounded failure, never hang
        }
    }
    __syncthreads();
}

// ---------------------------------------------------------------------------
// Fused LSTM GEMM tile: 16x16 (batch x hidden) of all 4 gates, 4 waves split
// K, all-wave LDS reduce + parallel epilogue. A-operands via coherent loads;
// weight loads normally cached (read-only, stay in L2 across all slots).
// Epilogue packs bf16 pairs and stores via coherent 32-bit stores.
// ---------------------------------------------------------------------------
__device__ __forceinline__ void gemm_lstm_tile(
    int tid, int jt, int mt, float* red,
    const __bf16* Ah, const __bf16* Al, int KS,
    const __bf16* W, int nsteps,
    const float* b1, const float* b2, float* cst,
    __bf16* d1h, __bf16* d1l, int st1, int off1,
    __bf16* d2h, __bf16* d2l, int st2, int off2, int clip2)
{
    const int wave = tid >> 6, lane = tid & 63;
    const int l15 = lane & 15, quad = lane >> 4;
    const int j0 = jt * 16, m0 = mt * 16;

    f32x4 acc[4];
    #pragma unroll
    for (int g = 0; g < 4; ++g)
        #pragma unroll
        for (int i = 0; i < 4; ++i) acc[g][i] = 0.f;

    const int ks = (wave * nsteps) >> 2;
    const int ke = ((wave + 1) * nsteps) >> 2;

    size_t aoff = (size_t)(m0 + l15) * KS + ks * 32 + quad * 8;
    size_t woff[4];
    #pragma unroll
    for (int g = 0; g < 4; ++g)
        woff[g] = (size_t)(g * 512 + j0 + l15) * KS + ks * 32 + quad * 8;

    for (int s = ks; s < ke; ++s) {
        bf16x8 ah = ldA(Ah + aoff);
        bf16x8 al = ldA(Al + aoff);
        aoff += 32;
        #pragma unroll
        for (int g = 0; g < 4; ++g) {
            bf16x8 wh = *(const bf16x8*)(W + woff[g]);
            woff[g] += 32;
            acc[g] = __builtin_amdgcn_mfma_f32_16x16x32_bf16(ah, wh, acc[g], 0, 0, 0);
            acc[g] = __builtin_amdgcn_mfma_f32_16x16x32_bf16(al, wh, acc[g], 0, 0, 0);
        }
    }

    #pragma unroll
    for (int g = 0; g < 4; ++g)
        #pragma unroll
        for (int r = 0; r < 4; ++r)
            red[(g * 4 + r) * 256 + wave * 64 + lane] = acc[g][r];
    __syncthreads();

    const int col = j0 + l15;
    const int m = m0 + quad * 4 + wave;
    float gv[4];
    #pragma unroll
    for (int g = 0; g < 4; ++g) {
        const float* rg = red + (g * 4 + wave) * 256;
        gv[g] = rg[lane] + rg[64 + lane] + rg[128 + lane] + rg[192 + lane]
              + b1[g * 512 + col] + b2[g * 512 + col];
    }
    float cold = cst[m * H_ + col];            // block-local across slots
    float cn = sigmoidf_(gv[1]) * cold + sigmoidf_(gv[0]) * tanhf_(gv[2]);
    cst[m * H_ + col] = cn;
    float h  = sigmoidf_(gv[3]) * tanhf_(cn);
    float h2 = clip2 ? fminf(fmaxf(h, -CLIP_), CLIP_) : h;

    float hO  = __shfl_xor(h, 1);
    float h2O = __shfl_xor(h2, 1);
    if (!(lane & 1)) {
        __bf16 a0 = (__bf16)h,  a1 = (__bf16)hO;
        st32(&d1h[(size_t)m * st1 + off1 + col], pk(a0, a1));
        st32(&d1l[(size_t)m * st1 + off1 + col],
             pk((__bf16)(h - (float)a0), (__bf16)(hO - (float)a1)));
        __bf16 b0 = (__bf16)h2, b1v = (__bf16)h2O;
        st32(&d2h[(size_t)m * st2 + off2 + col], pk(b0, b1v));
        st32(&d2l[(size_t)m * st2 + off2 + col],
             pk((__bf16)(h2 - (float)b0), (__bf16)(h2O - (float)b1v)));
    }
    __syncthreads();
}

// ---------------------------------------------------------------------------
// Plain GEMM tile (out projection). Output C is host-read only -> normal
// stores (kernel-end writeback covers it).
// ---------------------------------------------------------------------------
__device__ __forceinline__ void gemm_plain_tile(
    int tid, int nt, int mt, float* red,
    const __bf16* Ah, const __bf16* Al, int AS,
    const __bf16* W, int WS,
    int nsteps, const float* bias, float* C, int ldc)
{
    const int wave = tid >> 6, lane = tid & 63;
    const int l15 = lane & 15, quad = lane >> 4;
    const int n0 = nt * 16, m0 = mt * 16;

    f32x4 acc;
    #pragma unroll
    for (int i = 0; i < 4; ++i) acc[i] = 0.f;

    const int ks = (wave * nsteps) >> 2;
    const int ke = ((wave + 1) * nsteps) >> 2;

    size_t aoff = (size_t)(m0 + l15) * AS + ks * 32 + quad * 8;
    size_t woff = (size_t)(n0 + l15) * WS + ks * 32 + quad * 8;

    for (int s = ks; s < ke; ++s) {
        bf16x8 ah = ldA(Ah + aoff);
        bf16x8 al = ldA(Al + aoff);
        bf16x8 wh = *(const bf16x8*)(W + woff);
        aoff += 32; woff += 32;
        acc = __builtin_amdgcn_mfma_f32_16x16x32_bf16(ah, wh, acc, 0, 0, 0);
        acc = __builtin_amdgcn_mfma_f32_16x16x32_bf16(al, wh, acc, 0, 0, 0);
    }

    #pragma unroll
    for (int r = 0; r < 4; ++r) red[r * 256 + wave * 64 + lane] = acc[r];
    __syncthreads();

    const int col = n0 + l15;
    const int m = m0 + quad * 4 + wave;
    const float* rg = red + wave * 256;
    float v = rg[lane] + rg[64 + lane] + rg[128 + lane] + rg[192 + lane] + bias[col];
    C[(size_t)m * ldc + col] = v;
    __syncthreads();
}

// ---------------------------------------------------------------------------
// iface GEMM tile: S = act(out @ Wif^T + bif). A 2-limb x W 2-limb, 3 MFMAs
// per K-step. S written via coherent f32 stores (read by M blocks).
// ---------------------------------------------------------------------------
__device__ __forceinline__ void gemm_iface_tile(
    int tid, int jt, int mt, float* red,
    const __bf16* Ah, const __bf16* Al, int AS,
    const __bf16* Wh, const __bf16* Wl,
    const float* bif, float* Sout)
{
    const int wave = tid >> 6, lane = tid & 63;
    const int l15 = lane & 15, quad = lane >> 4;
    const int n0 = jt * 16, m0 = mt * 16;

    f32x4 acc;
    #pragma unroll
    for (int i = 0; i < 4; ++i) acc[i] = 0.f;

    size_t aoff = (size_t)(m0 + l15) * AS + wave * 128 + quad * 8;
    size_t woff = (size_t)(n0 + l15) * 512 + wave * 128 + quad * 8;

    #pragma unroll
    for (int s = 0; s < 4; ++s) {
        bf16x8 ah = ldA(Ah + aoff);
        bf16x8 al = ldA(Al + aoff);
        bf16x8 wh = *(const bf16x8*)(Wh + woff);
        bf16x8 wl = *(const bf16x8*)(Wl + woff);
        aoff += 32; woff += 32;
        acc = __builtin_amdgcn_mfma_f32_16x16x32_bf16(ah, wh, acc, 0, 0, 0);
        acc = __builtin_amdgcn_mfma_f32_16x16x32_bf16(al, wh, acc, 0, 0, 0);
        acc = __builtin_amdgcn_mfma_f32_16x16x32_bf16(ah, wl, acc, 0, 0, 0);
    }

    #pragma unroll
    for (int r = 0; r < 4; ++r) red[r * 256 + wave * 64 + lane] = acc[r];
    __syncthreads();

    const int o = n0 + l15;
    if (o < IFACE_) {
        const int m = m0 + quad * 4 + wave;
        const float* rg = red + wave * 256;
        float v = rg[lane] + rg[64 + lane] + rg[128 + lane] + rg[192 + lane] + bif[o];
        float rr;
        if (o < 80)        rr = tanhf_(v);
        else if (o < 84)   rr = softplusf_(v);
        else if (o < 104)  rr = tanhf_(v);
        else if (o < 105)  rr = softplusf_(v);
        else if (o < 125)  rr = sigmoidf_(v);
        else if (o < 145)  rr = tanhf_(v);
        else if (o < 151)  rr = sigmoidf_(v);
        else               rr = v;
        st32f(&Sout[(size_t)m * IFP_ + o], rr);
    }
    __syncthreads();
}

// ---------------------------------------------------------------------------
// DNC memory-step core. State arrays are block-local across slots (same block
// every slot in the persistent kernel) -> normal accesses. rv output is read
// by A/B blocks -> coherent paired stores.
// ---------------------------------------------------------------------------
__device__ void mem_core(int b, int tid, float* S,
    float* mem, float* link, float* prec, float* rw,
    float* ww, float* usage, __bf16* rvh, __bf16* rvl, int rvst)
{
    float* sif     = S;
    float* modes   = S + 164;
    float* wwnewS  = S + 208;
    float* precold = S + 224;
    float* rwold   = S + 240;
    float* rwnewS  = S + 304;
    float* lnk     = S + 368;   // 256
    float* memS    = S + 624;   // 320

    if (tid < M_)       precold[tid] = prec[(size_t)b * M_ + tid];
    if (tid < R_ * M_)  rwold[tid]   = rw[(size_t)b * R_ * M_ + tid];
    if (tid < M_ * M_)  lnk[tid]     = link[(size_t)b * M_ * M_ + tid];
    for (int i = tid; i < M_ * WC_; i += 256) memS[i] = mem[(size_t)b * M_ * WC_ + i];
    if (tid < R_) {
        float a0 = sif[151 + tid * 3], a1 = sif[152 + tid * 3], a2 = sif[153 + tid * 3];
        float mx = fmaxf(a0, fmaxf(a1, a2));
        float e0 = __expf(a0 - mx), e1 = __expf(a1 - mx), e2 = __expf(a2 - mx);
        float s = e0 + e1 + e2;
        modes[tid * 3 + 0] = e0 / s; modes[tid * 3 + 1] = e1 / s; modes[tid * 3 + 2] = e2 / s;
    }
    __syncthreads();

    if (tid < M_) {
        const int m = tid;
        float wwold = ww[(size_t)b * M_ + m];
        float u = usage[(size_t)b * M_ + m];
        u = u + (1.f - u) * wwold;
        float psi = 1.f;
        #pragma unroll
        for (int r = 0; r < R_; ++r) psi *= (1.f - sif[145 + r] * rwold[r * 16 + m]);
        u *= psi;

        float kn2 = 0.f, mn2 = 0.f, dot = 0.f;
        #pragma unroll
        for (int w = 0; w < WC_; ++w) {
            float kv = sif[84 + w], mv = memS[m * WC_ + w];
            kn2 += kv * kv; mn2 += mv * mv; dot += kv * mv;
        }
        float c = dot / ((sqrtf(kn2) + EPS_) * (sqrtf(mn2) + EPS_)) * sif[104];
        float mx = c;
        #pragma unroll
        for (int off = 8; off; off >>= 1) mx = fmaxf(mx, __shfl_xor(mx, off, 16));
        float e = __expf(c - mx);
        float se = e;
        #pragma unroll
        for (int off = 8; off; off >>= 1) se += __shfl_xor(se, off, 16);
        float wcw = e / se;

        float uu = DELTA_ + (1.f - DELTA_) * u;
        int rank = 0;
        #pragma unroll
        for (int j = 0; j < 16; ++j) {
            float uj = __shfl(uu, j, 16);
            if (uj < uu || (uj == uu && j < m)) ++rank;
        }
        float prod = 1.f;
        #pragma unroll
        for (int j = 0; j < 16; ++j) {
            float uj = __shfl(uu, j, 16);
            int   rj = __shfl(rank, j, 16);
            if (rj < rank) prod *= uj;
        }
        float alloc = (1.f - uu) * prod;

        float ag = sif[149], wg = sif[150];
        float wwn = wg * (ag * alloc + (1.f - ag) * wcw);
        float sw = wwn;
        #pragma unroll
        for (int off = 8; off; off >>= 1) sw += __shfl_xor(sw, off, 16);

        wwnewS[m] = wwn;
        usage[(size_t)b * M_ + m] = u;
        ww[(size_t)b * M_ + m]    = wwn;
        prec[(size_t)b * M_ + m]  = (1.f - sw) * precold[m] + wwn;
    }
    __syncthreads();

    for (int i = tid; i < M_ * WC_; i += 256) {
        int m = i / WC_, w = i - m * WC_;
        float nm = memS[i] * (1.f - wwnewS[m] * sif[105 + w]) + wwnewS[m] * sif[125 + w];
        memS[i] = nm;
        mem[(size_t)b * M_ * WC_ + i] = nm;
    }
    if (tid < M_ * M_) {
        int i = tid >> 4, j = tid & 15;
        float v = (1.f - wwnewS[i] - wwnewS[j]) * lnk[tid] + wwnewS[i] * precold[j];
        if (i == j) v = 0.f;
        lnk[tid] = v;
        link[(size_t)b * M_ * M_ + tid] = v;
    }
    __syncthreads();

    if (tid < 64) {
        const int r = tid >> 4, m = tid & 15;
        float kn2 = 0.f, mn2 = 0.f, dot = 0.f;
        #pragma unroll
        for (int w = 0; w < WC_; ++w) {
            float kv = sif[r * WC_ + w], mv = memS[m * WC_ + w];
            kn2 += kv * kv; mn2 += mv * mv; dot += kv * mv;
        }
        float c = dot / ((sqrtf(kn2) + EPS_) * (sqrtf(mn2) + EPS_)) * sif[80 + r];
        float mx = c;
        #pragma unroll
        for (int off = 8; off; off >>= 1) mx = fmaxf(mx, __shfl_xor(mx, off, 16));
        float e = __expf(c - mx);
        float se = e;
        #pragma unroll
        for (int off = 8; off; off >>= 1) se += __shfl_xor(se, off, 16);
        float rc = e / se;

        float fwd = 0.f, bwd = 0.f;
        #pragma unroll
        for (int j = 0; j < M_; ++j) fwd += lnk[m * 16 + j] * rwold[r * 16 + j];
        #pragma unroll
        for (int i2 = 0; i2 < M_; ++i2) bwd += rwold[r * 16 + i2] * lnk[i2 * 16 + m];
        float v = modes[r * 3 + 0] * bwd + modes[r * 3 + 1] * fwd + modes[r * 3 + 2] * rc;
        rwnewS[tid] = v;
        rw[(size_t)b * R_ * M_ + tid] = v;
    }
    __syncthreads();

    if (tid < RW_) {
        int r = tid / WC_, w = tid - r * WC_;
        float s = 0.f;
        #pragma unroll
        for (int m = 0; m < M_; ++m) s += rwnewS[r * 16 + m] * memS[m * WC_ + w];
        float sO = __shfl_xor(s, 1);
        if (!(tid & 1)) {
            __bf16 a0 = (__bf16)s, a1 = (__bf16)sO;
            st32(&rvh[(size_t)b * rvst + IN_ + tid], pk(a0, a1));
            st32(&rvl[(size_t)b * rvst + IN_ + tid],
                 pk((__bf16)(s - (float)a0), (__bf16)(sO - (float)a1)));
        }
    }
    __syncthreads();
}

__device__ void mem_group(int b, int tid, float* smem, const float* Sbuf,
    float* mem, float* link, float* prec, float* rw, float* ww, float* usage,
    __bf16* rvh, __bf16* rvl, int rvst)
{
    float* S = smem;
    for (int i = tid; i < IFACE_; i += 256) S[i] = ld32f(Sbuf + (size_t)b * IFP_ + i);
    __syncthreads();
    mem_core(b, tid, S, mem, link, prec, rw, ww, usage, rvh, rvl, rvst);
}

// ---------------------------------------------------------------------------
// Persistent kernel (normal launch): all 40 pipeline slots, fence-free grid
// barrier between slots. 1536 blocks = 6/CU co-resident. Stage map:
//   [0,256):      A0(t=s)
//   [256,512):    B0(t=s-1)
//   [512,768):    A1(t=s-4)
//   [768,1024):   B1(t=s-5)
//   [1024,1152):  M0(t=s-3)
//   [1152,1280):  M1(t=s-7)
//   [1280,1408):  Y(t=s-8)    128 blocks x 2 tiles
//   [1408,1452):  IF0(t=s-2)  44 blocks x 2 tiles
//   [1452,1496):  IF1(t=s-6)  44 blocks x 2 tiles
//   [1496,1528):  x(s+1) convert
//   [1528,1536):  idle (barrier participants)
// ---------------------------------------------------------------------------
__global__ __launch_bounds__(256, 6) void persist_kernel(P p)
{
    __shared__ float smem[4096];
    const int blk = blockIdx.x, tid = threadIdx.x;

    for (unsigned s = 0; s < T_ + 8; ++s) {
        if (blk < 256) {                       // A0(t=s)
            int t = (int)s;
            if (t < T_) {
                gemm_lstm_tile(tid, blk & 31, blk >> 5, smem,
                    p.a10h[t & 3], p.a10l[t & 3], K1P_, p.w10, K1P_ / 32,
                    p.bih0, p.bhh0, p.c00,
                    p.a10h[(t + 1) & 3], p.a10l[(t + 1) & 3], K1P_, NNIN_,
                    p.a20h[t & 3], p.a20l[t & 3], K2P_, 0, 0);
            }
        } else if (blk < 512) {                // B0(t=s-1)
            int t = (int)s - 1;
            if (t >= 0 && t < T_) {
                int b2 = blk - 256;
                gemm_lstm_tile(tid, b2 & 31, b2 >> 5, smem,
                    p.a20h[t & 3], p.a20l[t & 3], K2P_, p.w20, K2P_ / 32,
                    p.bih1, p.bhh1, p.c01,
                    p.a20h[(t + 1) & 3], p.a20l[(t + 1) & 3], K2P_, H_,
                    p.a11h[t & 3], p.a11l[t & 3], K1P_, 0, 1);
            }
        } else if (blk < 768) {                // A1(t=s-4)
            int t = (int)s - 4;
            if (t >= 0 && t < T_) {
                int b2 = blk - 512;
                gemm_lstm_tile(tid, b2 & 31, b2 >> 5, smem,
                    p.a11h[t & 3], p.a11l[t & 3], K1P_, p.w11, K1P_ / 32,
                    p.bih0 + 2048, p.bhh0 + 2048, p.c10,
                    p.a11h[(t + 1) & 3], p.a11l[(t + 1) & 3], K1P_, NNIN_,
                    p.a21h[t & 3], p.a21l[t & 3], K2P_, 0, 0);
            }
        } else if (blk < 1024) {               // B1(t=s-5)
            int t = (int)s - 5;
            if (t >= 0 && t < T_) {
                int b2 = blk - 768;
                gemm_lstm_tile(tid, b2 & 31, b2 >> 5, smem,
                    p.a21h[t & 3], p.a21l[t & 3], K2P_, p.w21, K2P_ / 32,
                    p.bih1 + 2048, p.bhh1 + 2048, p.c11,
                    p.a21h[(t + 1) & 3], p.a21l[(t + 1) & 3], K2P_, H_,
                    p.yh[t & 3], p.yl[t & 3], KOP_, 0, 1);
            }
        } else if (blk < 1152) {               // M0(t=s-3)
            int t = (int)s - 3;
            if (t >= 0 && t < T_) {
                mem_group(blk - 1024, tid, smem, p.S0[t & 1],
                    p.mem0, p.link0, p.prec0, p.rw0, p.ww0, p.us0,
                    p.a11h[t & 3], p.a11l[t & 3], K1P_);
            }
        } else if (blk < 1280) {               // M1(t=s-7)
            int t = (int)s - 7;
            if (t >= 0 && t < T_) {
                mem_group(blk - 1152, tid, smem, p.S1[t & 1],
                    p.mem1, p.link1, p.prec1, p.rw1, p.ww1, p.us1,
                    p.yh[t & 3], p.yl[t & 3], KOP_);
            }
        } else if (blk < 1408) {               // Y(t=s-8), 2 tiles
            int t = (int)s - 8;
            if (t >= 0 && t < T_) {
                int b2 = blk - 1280;
                gemm_plain_tile(tid, b2 & 31, b2 >> 5, smem,
                    p.yh[t & 3], p.yl[t & 3], KOP_, p.wo, KOP_, KOP_ / 32,
                    p.bout, p.out + (size_t)t * IN_, T_ * IN_);
                int tile = b2 + 128;
                gemm_plain_tile(tid, tile & 31, tile >> 5, smem,
                    p.yh[t & 3], p.yl[t & 3], KOP_, p.wo, KOP_, KOP_ / 32,
                    p.bout, p.out + (size_t)t * IN_, T_ * IN_);
            }
        } else if (blk < 1452) {               // IF0(t=s-2), 2 tiles
            int t = (int)s - 2;
            if (t >= 0 && t < T_) {
                int b2 = blk - 1408;
                gemm_iface_tile(tid, b2 % 11, b2 / 11, smem,
                    p.a11h[t & 3], p.a11l[t & 3], K1P_,
                    p.wif0h, p.wif0l, p.bif0, p.S0[t & 1]);
                int tile = b2 + 44;
                gemm_iface_tile(tid, tile % 11, tile / 11, smem,
                    p.a11h[t & 3], p.a11l[t & 3], K1P_,
                    p.wif0h, p.wif0l, p.bif0, p.S0[t & 1]);
            }
        } else if (blk < 1496) {               // IF1(t=s-6), 2 tiles
            int t = (int)s - 6;
            if (t >= 0 && t < T_) {
                int b2 = blk - 1452;
                gemm_iface_tile(tid, b2 % 11, b2 / 11, smem,
                    p.yh[t & 3], p.yl[t & 3], KOP_,
                    p.wif1h, p.wif1l, p.bif1, p.S1[t & 1]);
                int tile = b2 + 44;
                gemm_iface_tile(tid, tile % 11, tile / 11, smem,
                    p.yh[t & 3], p.yl[t & 3], KOP_,
                    p.wif1h, p.wif1l, p.bif1, p.S1[t & 1]);
            }
        } else if (blk < 1528) {               // x(s+1) convert (paired)
            int tn = (int)s + 1;
            if (tn < T_) {
                for (int i = (blk - 1496) * 256 + tid; i < B_ * IN_ / 2; i += 32 * 256) {
                    int idx = i * 2;
                    int b = idx >> 9, j = idx & 511;
                    const float* xp = p.x + ((size_t)b * T_ + tn) * IN_ + j;
                    float v0 = xp[0], v1 = xp[1];
                    __bf16 a0 = (__bf16)v0, a1 = (__bf16)v1;
                    st32(p.a10h[tn & 3] + (size_t)b * K1P_ + j, pk(a0, a1));
                    st32(p.a10l[tn & 3] + (size_t)b * K1P_ + j,
                         pk((__bf16)(v0 - (float)a0), (__bf16)(v1 - (float)a1)));
                }
            }
        }
        if (s != T_ + 7) grid_barrier(p.bar, blk, tid, s);
    }
}

// ---------------------------------------------------------------------------
// Setup kernels
// ---------------------------------------------------------------------------
struct ConvArgs { const float* s1; const float* s2; __bf16* dst; int K1, K2, Kd; };
struct ConvArgs4 { ConvArgs a[4]; };

__global__ __launch_bounds__(256) void conv_lstm(ConvArgs4 ca)
{
    ConvArgs c = ca.a[blockIdx.z];
    int k = blockIdx.x * 256 + threadIdx.x;
    if (k >= c.Kd) return;
    int n = blockIdx.y;
    float v = 0.f;
    if (k < c.K1) v = c.s1[(size_t)n * c.K1 + k];
    else if (k < c.K1 + c.K2) v = c.s2[(size_t)n * c.K2 + (k - c.K1)];
    c.dst[(size_t)n * c.Kd + k] = (__bf16)v;
}

__global__ __launch_bounds__(256) void conv_hi(
    const float* __restrict__ s1, int K1, const float* __restrict__ s2, int K2,
    int Nsrc, __bf16* __restrict__ hi, int Kd)
{
    int k = blockIdx.x * 256 + threadIdx.x;
    int n = blockIdx.y;
    if (k >= Kd) return;
    float v = 0.f;
    if (n < Nsrc) {
        if (k < K1) v = s1[(size_t)n * K1 + k];
        else if (k < K1 + K2) v = s2[(size_t)n * K2 + (k - K1)];
    }
    hi[(size_t)n * Kd + k] = (__bf16)v;
}

__global__ __launch_bounds__(256) void conv_hl(
    const float* __restrict__ src, int Nsrc, int K,
    __bf16* __restrict__ hi, __bf16* __restrict__ lo)
{
    int k = blockIdx.x * 256 + threadIdx.x;
    int n = blockIdx.y;
    if (k >= K) return;
    float v = (n < Nsrc) ? src[(size_t)n * K + k] : 0.f;
    split2(v, &hi[(size_t)n * K + k], &lo[(size_t)n * K + k]);
}

__global__ __launch_bounds__(256) void build_inp(const float* __restrict__ x,
                                                 __bf16* __restrict__ a1h,
                                                 __bf16* __restrict__ a1l)
{
    int idx = blockIdx.x * 256 + threadIdx.x;
    if (idx >= B_ * IN_) return;
    int b = idx >> 9, j = idx & 511;
    float v = x[(size_t)b * T_ * IN_ + j];
    split2(v, &a1h[b * K1P_ + j], &a1l[b * K1P_ + j]);
}

// ---------------------------------------------------------------------------
extern "C" void kernel_launch(void* const* d_in, const int* in_sizes, int n_in,
                              void* d_out, int out_size, void* d_ws, size_t ws_size,
                              hipStream_t stream)
{
    const float* x       = (const float*)d_in[0];
    const float* W_ih0   = (const float*)d_in[1];
    const float* W_hh0   = (const float*)d_in[2];
    const float* b_ih0   = (const float*)d_in[3];
    const float* b_hh0   = (const float*)d_in[4];
    const float* W_ih1   = (const float*)d_in[5];
    const float* W_hh1   = (const float*)d_in[6];
    const float* b_ih1   = (const float*)d_in[7];
    const float* b_hh1   = (const float*)d_in[8];
    const float* W_iface = (const float*)d_in[9];
    const float* b_iface = (const float*)d_in[10];
    const float* W_out   = (const float*)d_in[11];
    const float* b_out   = (const float*)d_in[12];

    P p;
    p.x = x;
    p.bih0 = b_ih0; p.bhh0 = b_hh0; p.bih1 = b_ih1; p.bhh1 = b_hh1;
    p.bif0 = b_iface; p.bif1 = b_iface + IFACE_;
    p.bout = b_out;
    p.out = (float*)d_out;

    char* ptr = (char*)d_ws;
    auto alloc = [&](size_t bytes) { char* r = ptr; ptr += (bytes + 255) & ~(size_t)255; return r; };

    // ---- zero zone (memset each call) ----
    char* zstart = ptr;
    for (int q = 0; q < 4; ++q) { p.a10h[q] = (__bf16*)alloc(B_ * K1P_ * 2); p.a10l[q] = (__bf16*)alloc(B_ * K1P_ * 2); }
    for (int q = 0; q < 4; ++q) { p.a11h[q] = (__bf16*)alloc(B_ * K1P_ * 2); p.a11l[q] = (__bf16*)alloc(B_ * K1P_ * 2); }
    for (int q = 0; q < 4; ++q) { p.a20h[q] = (__bf16*)alloc(B_ * K2P_ * 2); p.a20l[q] = (__bf16*)alloc(B_ * K2P_ * 2); }
    for (int q = 0; q < 4; ++q) { p.a21h[q] = (__bf16*)alloc(B_ * K2P_ * 2); p.a21l[q] = (__bf16*)alloc(B_ * K2P_ * 2); }
    for (int q = 0; q < 4; ++q) { p.yh[q]  = (__bf16*)alloc(B_ * KOP_ * 2);  p.yl[q]  = (__bf16*)alloc(B_ * KOP_ * 2); }
    p.c00 = (float*)alloc((size_t)B_ * H_ * 4);
    p.c01 = (float*)alloc((size_t)B_ * H_ * 4);
    p.c10 = (float*)alloc((size_t)B_ * H_ * 4);
    p.c11 = (float*)alloc((size_t)B_ * H_ * 4);
    p.mem0  = (float*)alloc((size_t)B_ * M_ * WC_ * 4);
    p.link0 = (float*)alloc((size_t)B_ * M_ * M_ * 4);
    p.prec0 = (float*)alloc((size_t)B_ * M_ * 4);
    p.rw0   = (float*)alloc((size_t)B_ * R_ * M_ * 4);
    p.ww0   = (float*)alloc((size_t)B_ * M_ * 4);
    p.us0   = (float*)alloc((size_t)B_ * M_ * 4);
    p.mem1  = (float*)alloc((size_t)B_ * M_ * WC_ * 4);
    p.link1 = (float*)alloc((size_t)B_ * M_ * M_ * 4);
    p.prec1 = (float*)alloc((size_t)B_ * M_ * 4);
    p.rw1   = (float*)alloc((size_t)B_ * R_ * M_ * 4);
    p.ww1   = (float*)alloc((size_t)B_ * M_ * 4);
    p.us1   = (float*)alloc((size_t)B_ * M_ * 4);
    p.bar   = (unsigned*)alloc(16384);
    size_t zbytes = (size_t)(ptr - zstart);

    // ---- weights (rewritten every call) ----
    p.w10 = (__bf16*)alloc(2048ull * K1P_ * 2);
    p.w11 = (__bf16*)alloc(2048ull * K1P_ * 2);
    p.w20 = (__bf16*)alloc(2048ull * K2P_ * 2);
    p.w21 = (__bf16*)alloc(2048ull * K2P_ * 2);
    p.wo  = (__bf16*)alloc(512ull * KOP_ * 2);
    p.wif0h = (__bf16*)alloc((size_t)IFP_ * 512 * 2);
    p.wif0l = (__bf16*)alloc((size_t)IFP_ * 512 * 2);
    p.wif1h = (__bf16*)alloc((size_t)IFP_ * 512 * 2);
    p.wif1l = (__bf16*)alloc((size_t)IFP_ * 512 * 2);
    for (int q = 0; q < 2; ++q) p.S0[q] = (float*)alloc((size_t)B_ * IFP_ * 4);
    for (int q = 0; q < 2; ++q) p.S1[q] = (float*)alloc((size_t)B_ * IFP_ * 4);

    hipMemsetAsync(zstart, 0, zbytes, stream);

    ConvArgs4 ca;
    ca.a[0] = { W_ih0,                 W_hh0,                 p.w10, NNIN_, H_, K1P_ };
    ca.a[1] = { W_ih0 + 2048ull*NNIN_, W_hh0 + 2048ull*H_,    p.w11, NNIN_, H_, K1P_ };
    ca.a[2] = { W_ih1,                 W_hh1,                 p.w20, H_,    H_, K2P_ };
    ca.a[3] = { W_ih1 + 2048ull*H_,    W_hh1 + 2048ull*H_,    p.w21, H_,    H_, K2P_ };
    conv_lstm<<<dim3((K1P_ + 255) / 256, 2048, 4), 256, 0, stream>>>(ca);

    conv_hi<<<dim3((KOP_ + 255) / 256, 512), 256, 0, stream>>>(
        W_out, NNIN_, nullptr, 0, 512, p.wo, KOP_);
    conv_hl<<<dim3(2, IFP_), 256, 0, stream>>>(
        W_iface, IFACE_, 512, p.wif0h, p.wif0l);
    conv_hl<<<dim3(2, IFP_), 256, 0, stream>>>(
        W_iface + (size_t)IFACE_ * 512, IFACE_, 512, p.wif1h, p.wif1l);
    build_inp<<<(B_ * IN_ + 255) / 256, 256, 0, stream>>>(x, p.a10h[0], p.a10l[0]);

    // single persistent launch: 40 slots, fence-free grid barriers
    persist_kernel<<<NBLK_, 256, 0, stream>>>(p);
}

// Round 7
// 1158.466 us; speedup vs baseline: 1.2231x; 1.2231x over previous
//
#include <hip/hip_runtime.h>
#include <hip/hip_bf16.h>
#include <math.h>

#define B_ 128
#define T_ 32
#define IN_ 512
#define H_ 512
#define M_ 16
#define WC_ 20
#define R_ 4
#define RW_ 80
#define NNIN_ 592
#define IFACE_ 163
#define IFP_ 176
#define K1P_ 1120
#define K2P_ 1024
#define KOP_ 608
#define CLIP_ 20.0f
#define EPS_ 1e-6f
#define DELTA_ 5e-6f

typedef __bf16 bf16x8 __attribute__((ext_vector_type(8)));
typedef float f32x4 __attribute__((ext_vector_type(4)));

__device__ __forceinline__ float sigmoidf_(float x) { return 1.0f / (1.0f + __expf(-x)); }
__device__ __forceinline__ float tanhf_(float x) {
    float e = __expf(-2.f * fabsf(x));
    float t = (1.f - e) / (1.f + e);
    return copysignf(t, x);
}
__device__ __forceinline__ float softplusf_(float x) {
    return fmaxf(x, 0.0f) + log1pf(__expf(-fabsf(x)));
}
__device__ __forceinline__ void split2(float v, __bf16* hp, __bf16* lp) {
    __bf16 h = (__bf16)v;
    *hp = h;
    *lp = (__bf16)(v - (float)h);
}

// ---------------------------------------------------------------------------
// Parameter block. LSTM/out weights: single bf16 limb. iface weights: 2-limb
// bf16 (hi+lo). Activations split hi/lo.
// ---------------------------------------------------------------------------
struct P {
    const float *x, *bih0, *bhh0, *bih1, *bhh1, *bif0, *bif1, *bout;
    float* out;
    __bf16 *a10h[4], *a10l[4];   // [x | 0 | h00], stride K1P
    __bf16 *a11h[4], *a11l[4];   // [out0 | rv0 | h10], stride K1P
    __bf16 *a20h[4], *a20l[4];   // [h0A | h01], stride K2P
    __bf16 *a21h[4], *a21l[4];   // [h1A | h11], stride K2P
    __bf16 *yh[4],  *yl[4];      // [out1 | rv1 | pad], stride KOP
    float *c00, *c01, *c10, *c11;
    float *mem0, *link0, *prec0, *rw0, *ww0, *us0;
    float *mem1, *link1, *prec1, *rw1, *ww1, *us1;
    __bf16 *w10, *w20, *w11, *w21, *wo;
    __bf16 *wif0h, *wif0l, *wif1h, *wif1l;   // [IFP_ x 512]
    float *S0[2], *S1[2];                    // [B_ x IFP_] activated iface
};

// ---------------------------------------------------------------------------
// Fused LSTM GEMM tile: 16x16 (batch x hidden) of all 4 gates, 4 waves split
// K. All-wave LDS reduce; wave w runs the LSTM pointwise epilogue for row
// subset r=w. red needs 16*256 floats (16 KB).
// ---------------------------------------------------------------------------
__device__ __forceinline__ void gemm_lstm_tile(
    int tid, int jt, int mt, float* red,
    const __bf16* Ah, const __bf16* Al, int KS,
    const __bf16* W, int nsteps,
    const float* b1, const float* b2, float* cst,
    __bf16* d1h, __bf16* d1l, int st1, int off1,
    __bf16* d2h, __bf16* d2l, int st2, int off2, int clip2)
{
    const int wave = tid >> 6, lane = tid & 63;
    const int l15 = lane & 15, quad = lane >> 4;
    const int j0 = jt * 16, m0 = mt * 16;

    f32x4 acc[4];
    #pragma unroll
    for (int g = 0; g < 4; ++g)
        #pragma unroll
        for (int i = 0; i < 4; ++i) acc[g][i] = 0.f;

    const int ks = (wave * nsteps) >> 2;
    const int ke = ((wave + 1) * nsteps) >> 2;

    size_t aoff = (size_t)(m0 + l15) * KS + ks * 32 + quad * 8;
    size_t woff[4];
    #pragma unroll
    for (int g = 0; g < 4; ++g)
        woff[g] = (size_t)(g * 512 + j0 + l15) * KS + ks * 32 + quad * 8;

    for (int s = ks; s < ke; ++s) {
        bf16x8 ah = *(const bf16x8*)(Ah + aoff);
        bf16x8 al = *(const bf16x8*)(Al + aoff);
        aoff += 32;
        #pragma unroll
        for (int g = 0; g < 4; ++g) {
            bf16x8 wh = *(const bf16x8*)(W + woff[g]);
            woff[g] += 32;
            acc[g] = __builtin_amdgcn_mfma_f32_16x16x32_bf16(ah, wh, acc[g], 0, 0, 0);
            acc[g] = __builtin_amdgcn_mfma_f32_16x16x32_bf16(al, wh, acc[g], 0, 0, 0);
        }
    }

    #pragma unroll
    for (int g = 0; g < 4; ++g)
        #pragma unroll
        for (int r = 0; r < 4; ++r)
            red[(g * 4 + r) * 256 + wave * 64 + lane] = acc[g][r];
    __syncthreads();

    const int col = j0 + l15;
    const int m = m0 + quad * 4 + wave;
    float gv[4];
    #pragma unroll
    for (int g = 0; g < 4; ++g) {
        const float* rg = red + (g * 4 + wave) * 256;
        gv[g] = rg[lane] + rg[64 + lane] + rg[128 + lane] + rg[192 + lane]
              + b1[g * 512 + col] + b2[g * 512 + col];
    }
    float cold = cst[m * H_ + col];
    float cn = sigmoidf_(gv[1]) * cold + sigmoidf_(gv[0]) * tanhf_(gv[2]);
    cst[m * H_ + col] = cn;
    float h = sigmoidf_(gv[3]) * tanhf_(cn);
    split2(h, &d1h[(size_t)m * st1 + off1 + col], &d1l[(size_t)m * st1 + off1 + col]);
    float h2 = clip2 ? fminf(fmaxf(h, -CLIP_), CLIP_) : h;
    split2(h2, &d2h[(size_t)m * st2 + off2 + col], &d2l[(size_t)m * st2 + off2 + col]);
}

// ---------------------------------------------------------------------------
// Plain GEMM tile (out projection), W single-limb, all-wave epilogue.
// ---------------------------------------------------------------------------
__device__ __forceinline__ void gemm_plain_tile(
    int tid, int nt, int mt, float* red,
    const __bf16* Ah, const __bf16* Al, int AS,
    const __bf16* W, int WS,
    int nsteps, const float* bias, float* C, int ldc)
{
    const int wave = tid >> 6, lane = tid & 63;
    const int l15 = lane & 15, quad = lane >> 4;
    const int n0 = nt * 16, m0 = mt * 16;

    f32x4 acc;
    #pragma unroll
    for (int i = 0; i < 4; ++i) acc[i] = 0.f;

    const int ks = (wave * nsteps) >> 2;
    const int ke = ((wave + 1) * nsteps) >> 2;

    size_t aoff = (size_t)(m0 + l15) * AS + ks * 32 + quad * 8;
    size_t woff = (size_t)(n0 + l15) * WS + ks * 32 + quad * 8;

    for (int s = ks; s < ke; ++s) {
        bf16x8 ah = *(const bf16x8*)(Ah + aoff);
        bf16x8 al = *(const bf16x8*)(Al + aoff);
        bf16x8 wh = *(const bf16x8*)(W + woff);
        aoff += 32; woff += 32;
        acc = __builtin_amdgcn_mfma_f32_16x16x32_bf16(ah, wh, acc, 0, 0, 0);
        acc = __builtin_amdgcn_mfma_f32_16x16x32_bf16(al, wh, acc, 0, 0, 0);
    }

    #pragma unroll
    for (int r = 0; r < 4; ++r) red[r * 256 + wave * 64 + lane] = acc[r];
    __syncthreads();

    const int col = n0 + l15;
    const int m = m0 + quad * 4 + wave;
    const float* rg = red + wave * 256;
    float v = rg[lane] + rg[64 + lane] + rg[128 + lane] + rg[192 + lane] + bias[col];
    C[(size_t)m * ldc + col] = v;
}

// ---------------------------------------------------------------------------
// iface GEMM tile: S = act(out @ Wif^T + bif). A 2-limb x W 2-limb, 3 MFMAs
// per K-step (al*wl dropped). K = 512 fixed -> 16 steps, 4 per wave.
// ---------------------------------------------------------------------------
__device__ __forceinline__ void gemm_iface_tile(
    int tid, int jt, int mt, float* red,
    const __bf16* Ah, const __bf16* Al, int AS,
    const __bf16* Wh, const __bf16* Wl,
    const float* bif, float* Sout)
{
    const int wave = tid >> 6, lane = tid & 63;
    const int l15 = lane & 15, quad = lane >> 4;
    const int n0 = jt * 16, m0 = mt * 16;

    f32x4 acc;
    #pragma unroll
    for (int i = 0; i < 4; ++i) acc[i] = 0.f;

    size_t aoff = (size_t)(m0 + l15) * AS + wave * 128 + quad * 8;
    size_t woff = (size_t)(n0 + l15) * 512 + wave * 128 + quad * 8;

    #pragma unroll
    for (int s = 0; s < 4; ++s) {
        bf16x8 ah = *(const bf16x8*)(Ah + aoff);
        bf16x8 al = *(const bf16x8*)(Al + aoff);
        bf16x8 wh = *(const bf16x8*)(Wh + woff);
        bf16x8 wl = *(const bf16x8*)(Wl + woff);
        aoff += 32; woff += 32;
        acc = __builtin_amdgcn_mfma_f32_16x16x32_bf16(ah, wh, acc, 0, 0, 0);
        acc = __builtin_amdgcn_mfma_f32_16x16x32_bf16(al, wh, acc, 0, 0, 0);
        acc = __builtin_amdgcn_mfma_f32_16x16x32_bf16(ah, wl, acc, 0, 0, 0);
    }

    #pragma unroll
    for (int r = 0; r < 4; ++r) red[r * 256 + wave * 64 + lane] = acc[r];
    __syncthreads();

    const int o = n0 + l15;
    if (o < IFACE_) {
        const int m = m0 + quad * 4 + wave;
        const float* rg = red + wave * 256;
        float v = rg[lane] + rg[64 + lane] + rg[128 + lane] + rg[192 + lane] + bif[o];
        float rr;
        if (o < 80)        rr = tanhf_(v);
        else if (o < 84)   rr = softplusf_(v);
        else if (o < 104)  rr = tanhf_(v);
        else if (o < 105)  rr = softplusf_(v);
        else if (o < 125)  rr = sigmoidf_(v);
        else if (o < 145)  rr = tanhf_(v);
        else if (o < 151)  rr = sigmoidf_(v);
        else               rr = v;
        Sout[(size_t)m * IFP_ + o] = rr;
    }
}

// ---------------------------------------------------------------------------
// DNC memory-step core (one block per batch element, 256 threads). 16-lane
// register reductions (shfl_xor softmax; rank-based alloc == stable argsort
// + exclusive cumprod).
// ---------------------------------------------------------------------------
__device__ void mem_core(int b, int tid, float* S,
    float* mem, float* link, float* prec, float* rw,
    float* ww, float* usage, __bf16* rvh, __bf16* rvl, int rvst)
{
    float* sif     = S;
    float* modes   = S + 164;
    float* wwnewS  = S + 208;
    float* precold = S + 224;
    float* rwold   = S + 240;
    float* rwnewS  = S + 304;
    float* lnk     = S + 368;   // 256
    float* memS    = S + 624;   // 320

    if (tid < M_)       precold[tid] = prec[(size_t)b * M_ + tid];
    if (tid < R_ * M_)  rwold[tid]   = rw[(size_t)b * R_ * M_ + tid];
    if (tid < M_ * M_)  lnk[tid]     = link[(size_t)b * M_ * M_ + tid];
    for (int i = tid; i < M_ * WC_; i += 256) memS[i] = mem[(size_t)b * M_ * WC_ + i];
    if (tid < R_) {
        float a0 = sif[151 + tid * 3], a1 = sif[152 + tid * 3], a2 = sif[153 + tid * 3];
        float mx = fmaxf(a0, fmaxf(a1, a2));
        float e0 = __expf(a0 - mx), e1 = __expf(a1 - mx), e2 = __expf(a2 - mx);
        float s = e0 + e1 + e2;
        modes[tid * 3 + 0] = e0 / s; modes[tid * 3 + 1] = e1 / s; modes[tid * 3 + 2] = e2 / s;
    }
    __syncthreads();

    if (tid < M_) {
        const int m = tid;
        float wwold = ww[(size_t)b * M_ + m];
        float u = usage[(size_t)b * M_ + m];
        u = u + (1.f - u) * wwold;
        float psi = 1.f;
        #pragma unroll
        for (int r = 0; r < R_; ++r) psi *= (1.f - sif[145 + r] * rwold[r * 16 + m]);
        u *= psi;

        float kn2 = 0.f, mn2 = 0.f, dot = 0.f;
        #pragma unroll
        for (int w = 0; w < WC_; ++w) {
            float kv = sif[84 + w], mv = memS[m * WC_ + w];
            kn2 += kv * kv; mn2 += mv * mv; dot += kv * mv;
        }
        float c = dot / ((sqrtf(kn2) + EPS_) * (sqrtf(mn2) + EPS_)) * sif[104];
        float mx = c;
        #pragma unroll
        for (int off = 8; off; off >>= 1) mx = fmaxf(mx, __shfl_xor(mx, off, 16));
        float e = __expf(c - mx);
        float se = e;
        #pragma unroll
        for (int off = 8; off; off >>= 1) se += __shfl_xor(se, off, 16);
        float wcw = e / se;

        float uu = DELTA_ + (1.f - DELTA_) * u;
        int rank = 0;
        #pragma unroll
        for (int j = 0; j < 16; ++j) {
            float uj = __shfl(uu, j, 16);
            if (uj < uu || (uj == uu && j < m)) ++rank;
        }
        float prod = 1.f;
        #pragma unroll
        for (int j = 0; j < 16; ++j) {
            float uj = __shfl(uu, j, 16);
            int   rj = __shfl(rank, j, 16);
            if (rj < rank) prod *= uj;
        }
        float alloc = (1.f - uu) * prod;

        float ag = sif[149], wg = sif[150];
        float wwn = wg * (ag * alloc + (1.f - ag) * wcw);
        float sw = wwn;
        #pragma unroll
        for (int off = 8; off; off >>= 1) sw += __shfl_xor(sw, off, 16);

        wwnewS[m] = wwn;
        usage[(size_t)b * M_ + m] = u;
        ww[(size_t)b * M_ + m]    = wwn;
        prec[(size_t)b * M_ + m]  = (1.f - sw) * precold[m] + wwn;
    }
    __syncthreads();

    for (int i = tid; i < M_ * WC_; i += 256) {
        int m = i / WC_, w = i - m * WC_;
        float nm = memS[i] * (1.f - wwnewS[m] * sif[105 + w]) + wwnewS[m] * sif[125 + w];
        memS[i] = nm;
        mem[(size_t)b * M_ * WC_ + i] = nm;
    }
    if (tid < M_ * M_) {
        int i = tid >> 4, j = tid & 15;
        float v = (1.f - wwnewS[i] - wwnewS[j]) * lnk[tid] + wwnewS[i] * precold[j];
        if (i == j) v = 0.f;
        lnk[tid] = v;
        link[(size_t)b * M_ * M_ + tid] = v;
    }
    __syncthreads();

    if (tid < 64) {
        const int r = tid >> 4, m = tid & 15;
        float kn2 = 0.f, mn2 = 0.f, dot = 0.f;
        #pragma unroll
        for (int w = 0; w < WC_; ++w) {
            float kv = sif[r * WC_ + w], mv = memS[m * WC_ + w];
            kn2 += kv * kv; mn2 += mv * mv; dot += kv * mv;
        }
        float c = dot / ((sqrtf(kn2) + EPS_) * (sqrtf(mn2) + EPS_)) * sif[80 + r];
        float mx = c;
        #pragma unroll
        for (int off = 8; off; off >>= 1) mx = fmaxf(mx, __shfl_xor(mx, off, 16));
        float e = __expf(c - mx);
        float se = e;
        #pragma unroll
        for (int off = 8; off; off >>= 1) se += __shfl_xor(se, off, 16);
        float rc = e / se;

        float fwd = 0.f, bwd = 0.f;
        #pragma unroll
        for (int j = 0; j < M_; ++j) fwd += lnk[m * 16 + j] * rwold[r * 16 + j];
        #pragma unroll
        for (int i2 = 0; i2 < M_; ++i2) bwd += rwold[r * 16 + i2] * lnk[i2 * 16 + m];
        float v = modes[r * 3 + 0] * bwd + modes[r * 3 + 1] * fwd + modes[r * 3 + 2] * rc;
        rwnewS[tid] = v;
        rw[(size_t)b * R_ * M_ + tid] = v;
    }
    __syncthreads();

    if (tid < RW_) {
        int r = tid / WC_, w = tid - r * WC_;
        float s = 0.f;
        #pragma unroll
        for (int m = 0; m < M_; ++m) s += rwnewS[r * 16 + m] * memS[m * WC_ + w];
        split2(s, &rvh[(size_t)b * rvst + IN_ + tid], &rvl[(size_t)b * rvst + IN_ + tid]);
    }
}

__device__ void mem_group(int b, int tid, float* smem, const float* Sbuf,
    float* mem, float* link, float* prec, float* rw, float* ww, float* usage,
    __bf16* rvh, __bf16* rvl, int rvst)
{
    float* S = smem;
    for (int i = tid; i < IFACE_; i += 256) S[i] = Sbuf[(size_t)b * IFP_ + i];
    __syncthreads();
    mem_core(b, tid, S, mem, link, prec, rw, ww, usage, rvh, rvl, rvst);
}

// ---------------------------------------------------------------------------
// One pipeline slot, XCD-pinned stage placement. Grid = 2048 blocks (full
// 8-blocks/CU capacity); default dispatch maps block i -> XCD i%8, so
// (xcd = blk&7, k = blk>>3) pins each stage-half to a fixed XCD every slot.
// LSTM stages are split by jt-half so each XCD's weight slice (2.1-2.3 MB)
// stays resident in its 4 MiB L2 across all 40 slots. Mapping is a perf
// heuristic only — correctness comes from launch-boundary coherence.
//   XCD0: A0 jt[0,16)  | Y nt[0,8)   | IF0 mt[0,4)
//   XCD1: A0 jt[16,32) | Y nt[8,16)  | IF0 mt[4,8)
//   XCD2: B0 jt[0,16)  | Y nt[16,24) | IF1 mt[0,4)
//   XCD3: B0 jt[16,32) | Y nt[24,32) | IF1 mt[4,8)
//   XCD4: A1 jt[0,16)  | M0 b[0,64)   | x chunks [0,16)
//   XCD5: A1 jt[16,32) | M0 b[64,128) | x chunks [16,32)
//   XCD6: B1 jt[0,16)  | M1 b[0,64)
//   XCD7: B1 jt[16,32) | M1 b[64,128)
// Stage time offsets: A0 t=s, B0 s-1, IF0 s-2, M0 s-3, A1 s-4, B1 s-5,
// IF1 s-6, M1 s-7, Y s-8, x-convert s+1.
// ---------------------------------------------------------------------------
__global__ __launch_bounds__(256, 8) void slot_kernel(P p, int s)
{
    __shared__ float smem[4096];
    const int blk = blockIdx.x, tid = threadIdx.x;
    const int xcd = blk & 7, k = blk >> 3;
    const int half = xcd & 1;

    if (xcd < 2) {
        if (k < 128) {                       // A0(t=s)
            int t = s;
            if (t < T_) {
                int jt = (k & 15) + half * 16, mt = k >> 4;
                gemm_lstm_tile(tid, jt, mt, smem,
                    p.a10h[t & 3], p.a10l[t & 3], K1P_, p.w10, K1P_ / 32,
                    p.bih0, p.bhh0, p.c00,
                    p.a10h[(t + 1) & 3], p.a10l[(t + 1) & 3], K1P_, NNIN_,
                    p.a20h[t & 3], p.a20l[t & 3], K2P_, 0, 0);
            }
        } else if (k < 192) {                // Y(t=s-8) quarter 0/1
            int t = s - 8;
            if (t >= 0 && t < T_) {
                int q = k - 128;
                gemm_plain_tile(tid, (q & 7) + half * 8, q >> 3, smem,
                    p.yh[t & 3], p.yl[t & 3], KOP_, p.wo, KOP_, KOP_ / 32,
                    p.bout, p.out + (size_t)t * IN_, T_ * IN_);
            }
        } else if (k < 236) {                // IF0(t=s-2) mt-half
            int t = s - 2;
            if (t >= 0 && t < T_) {
                int idx = k - 192;
                gemm_iface_tile(tid, idx % 11, idx / 11 + half * 4, smem,
                    p.a11h[t & 3], p.a11l[t & 3], K1P_,
                    p.wif0h, p.wif0l, p.bif0, p.S0[t & 1]);
            }
        }
    } else if (xcd < 4) {
        if (k < 128) {                       // B0(t=s-1)
            int t = s - 1;
            if (t >= 0 && t < T_) {
                int jt = (k & 15) + half * 16, mt = k >> 4;
                gemm_lstm_tile(tid, jt, mt, smem,
                    p.a20h[t & 3], p.a20l[t & 3], K2P_, p.w20, K2P_ / 32,
                    p.bih1, p.bhh1, p.c01,
                    p.a20h[(t + 1) & 3], p.a20l[(t + 1) & 3], K2P_, H_,
                    p.a11h[t & 3], p.a11l[t & 3], K1P_, 0, 1);
            }
        } else if (k < 192) {                // Y(t=s-8) quarter 2/3
            int t = s - 8;
            if (t >= 0 && t < T_) {
                int q = k - 128;
                gemm_plain_tile(tid, (q & 7) + 16 + half * 8, q >> 3, smem,
                    p.yh[t & 3], p.yl[t & 3], KOP_, p.wo, KOP_, KOP_ / 32,
                    p.bout, p.out + (size_t)t * IN_, T_ * IN_);
            }
        } else if (k < 236) {                // IF1(t=s-6) mt-half
            int t = s - 6;
            if (t >= 0 && t < T_) {
                int idx = k - 192;
                gemm_iface_tile(tid, idx % 11, idx / 11 + half * 4, smem,
                    p.yh[t & 3], p.yl[t & 3], KOP_,
                    p.wif1h, p.wif1l, p.bif1, p.S1[t & 1]);
            }
        }
    } else if (xcd < 6) {
        if (k < 128) {                       // A1(t=s-4)
            int t = s - 4;
            if (t >= 0 && t < T_) {
                int jt = (k & 15) + half * 16, mt = k >> 4;
                gemm_lstm_tile(tid, jt, mt, smem,
                    p.a11h[t & 3], p.a11l[t & 3], K1P_, p.w11, K1P_ / 32,
                    p.bih0 + 2048, p.bhh0 + 2048, p.c10,
                    p.a11h[(t + 1) & 3], p.a11l[(t + 1) & 3], K1P_, NNIN_,
                    p.a21h[t & 3], p.a21l[t & 3], K2P_, 0, 0);
            }
        } else if (k < 192) {                // M0(t=s-3) half
            int t = s - 3;
            if (t >= 0 && t < T_) {
                mem_group(k - 128 + half * 64, tid, smem, p.S0[t & 1],
                    p.mem0, p.link0, p.prec0, p.rw0, p.ww0, p.us0,
                    p.a11h[t & 3], p.a11l[t & 3], K1P_);
            }
        } else if (k < 208) {                // x(s+1) convert half
            int tn = s + 1;
            if (tn < T_) {
                int c = (k - 192) + half * 16;
                for (int i = c * 256 + tid; i < B_ * IN_; i += 32 * 256) {
                    int b = i >> 9, j = i & 511;
                    float v = p.x[((size_t)b * T_ + tn) * IN_ + j];
                    split2(v, &p.a10h[tn & 3][(size_t)b * K1P_ + j],
                              &p.a10l[tn & 3][(size_t)b * K1P_ + j]);
                }
            }
        }
    } else {
        if (k < 128) {                       // B1(t=s-5)
            int t = s - 5;
            if (t >= 0 && t < T_) {
                int jt = (k & 15) + half * 16, mt = k >> 4;
                gemm_lstm_tile(tid, jt, mt, smem,
                    p.a21h[t & 3], p.a21l[t & 3], K2P_, p.w21, K2P_ / 32,
                    p.bih1 + 2048, p.bhh1 + 2048, p.c11,
                    p.a21h[(t + 1) & 3], p.a21l[(t + 1) & 3], K2P_, H_,
                    p.yh[t & 3], p.yl[t & 3], KOP_, 0, 1);
            }
        } else if (k < 192) {                // M1(t=s-7) half
            int t = s - 7;
            if (t >= 0 && t < T_) {
                mem_group(k - 128 + half * 64, tid, smem, p.S1[t & 1],
                    p.mem1, p.link1, p.prec1, p.rw1, p.ww1, p.us1,
                    p.yh[t & 3], p.yl[t & 3], KOP_);
            }
        }
    }
}

// ---------------------------------------------------------------------------
// Setup kernels
// ---------------------------------------------------------------------------
struct ConvArgs { const float* s1; const float* s2; __bf16* dst; int K1, K2, Kd; };
struct ConvArgs4 { ConvArgs a[4]; };

__global__ __launch_bounds__(256) void conv_lstm(ConvArgs4 ca)
{
    ConvArgs c = ca.a[blockIdx.z];
    int k = blockIdx.x * 256 + threadIdx.x;
    if (k >= c.Kd) return;
    int n = blockIdx.y;
    float v = 0.f;
    if (k < c.K1) v = c.s1[(size_t)n * c.K1 + k];
    else if (k < c.K1 + c.K2) v = c.s2[(size_t)n * c.K2 + (k - c.K1)];
    c.dst[(size_t)n * c.Kd + k] = (__bf16)v;
}

__global__ __launch_bounds__(256) void conv_hi(
    const float* __restrict__ s1, int K1, const float* __restrict__ s2, int K2,
    int Nsrc, __bf16* __restrict__ hi, int Kd)
{
    int k = blockIdx.x * 256 + threadIdx.x;
    int n = blockIdx.y;
    if (k >= Kd) return;
    float v = 0.f;
    if (n < Nsrc) {
        if (k < K1) v = s1[(size_t)n * K1 + k];
        else if (k < K1 + K2) v = s2[(size_t)n * K2 + (k - K1)];
    }
    hi[(size_t)n * Kd + k] = (__bf16)v;
}

__global__ __launch_bounds__(256) void conv_hl(
    const float* __restrict__ src, int Nsrc, int K,
    __bf16* __restrict__ hi, __bf16* __restrict__ lo)
{
    int k = blockIdx.x * 256 + threadIdx.x;
    int n = blockIdx.y;
    if (k >= K) return;
    float v = (n < Nsrc) ? src[(size_t)n * K + k] : 0.f;
    split2(v, &hi[(size_t)n * K + k], &lo[(size_t)n * K + k]);
}

__global__ __launch_bounds__(256) void build_inp(const float* __restrict__ x,
                                                 __bf16* __restrict__ a1h,
                                                 __bf16* __restrict__ a1l)
{
    int idx = blockIdx.x * 256 + threadIdx.x;
    if (idx >= B_ * IN_) return;
    int b = idx >> 9, j = idx & 511;
    float v = x[(size_t)b * T_ * IN_ + j];
    split2(v, &a1h[b * K1P_ + j], &a1l[b * K1P_ + j]);
}

// ---------------------------------------------------------------------------
extern "C" void kernel_launch(void* const* d_in, const int* in_sizes, int n_in,
                              void* d_out, int out_size, void* d_ws, size_t ws_size,
                              hipStream_t stream)
{
    const float* x       = (const float*)d_in[0];
    const float* W_ih0   = (const float*)d_in[1];
    const float* W_hh0   = (const float*)d_in[2];
    const float* b_ih0   = (const float*)d_in[3];
    const float* b_hh0   = (const float*)d_in[4];
    const float* W_ih1   = (const float*)d_in[5];
    const float* W_hh1   = (const float*)d_in[6];
    const float* b_ih1   = (const float*)d_in[7];
    const float* b_hh1   = (const float*)d_in[8];
    const float* W_iface = (const float*)d_in[9];
    const float* b_iface = (const float*)d_in[10];
    const float* W_out   = (const float*)d_in[11];
    const float* b_out   = (const float*)d_in[12];

    P p;
    p.x = x;
    p.bih0 = b_ih0; p.bhh0 = b_hh0; p.bih1 = b_ih1; p.bhh1 = b_hh1;
    p.bif0 = b_iface; p.bif1 = b_iface + IFACE_;
    p.bout = b_out;
    p.out = (float*)d_out;

    char* ptr = (char*)d_ws;
    auto alloc = [&](size_t bytes) { char* r = ptr; ptr += (bytes + 255) & ~(size_t)255; return r; };

    // ---- zero zone (memset each call) ----
    char* zstart = ptr;
    for (int q = 0; q < 4; ++q) { p.a10h[q] = (__bf16*)alloc(B_ * K1P_ * 2); p.a10l[q] = (__bf16*)alloc(B_ * K1P_ * 2); }
    for (int q = 0; q < 4; ++q) { p.a11h[q] = (__bf16*)alloc(B_ * K1P_ * 2); p.a11l[q] = (__bf16*)alloc(B_ * K1P_ * 2); }
    for (int q = 0; q < 4; ++q) { p.a20h[q] = (__bf16*)alloc(B_ * K2P_ * 2); p.a20l[q] = (__bf16*)alloc(B_ * K2P_ * 2); }
    for (int q = 0; q < 4; ++q) { p.a21h[q] = (__bf16*)alloc(B_ * K2P_ * 2); p.a21l[q] = (__bf16*)alloc(B_ * K2P_ * 2); }
    for (int q = 0; q < 4; ++q) { p.yh[q]  = (__bf16*)alloc(B_ * KOP_ * 2);  p.yl[q]  = (__bf16*)alloc(B_ * KOP_ * 2); }
    p.c00 = (float*)alloc((size_t)B_ * H_ * 4);
    p.c01 = (float*)alloc((size_t)B_ * H_ * 4);
    p.c10 = (float*)alloc((size_t)B_ * H_ * 4);
    p.c11 = (float*)alloc((size_t)B_ * H_ * 4);
    p.mem0  = (float*)alloc((size_t)B_ * M_ * WC_ * 4);
    p.link0 = (float*)alloc((size_t)B_ * M_ * M_ * 4);
    p.prec0 = (float*)alloc((size_t)B_ * M_ * 4);
    p.rw0   = (float*)alloc((size_t)B_ * R_ * M_ * 4);
    p.ww0   = (float*)alloc((size_t)B_ * M_ * 4);
    p.us0   = (float*)alloc((size_t)B_ * M_ * 4);
    p.mem1  = (float*)alloc((size_t)B_ * M_ * WC_ * 4);
    p.link1 = (float*)alloc((size_t)B_ * M_ * M_ * 4);
    p.prec1 = (float*)alloc((size_t)B_ * M_ * 4);
    p.rw1   = (float*)alloc((size_t)B_ * R_ * M_ * 4);
    p.ww1   = (float*)alloc((size_t)B_ * M_ * 4);
    p.us1   = (float*)alloc((size_t)B_ * M_ * 4);
    size_t zbytes = (size_t)(ptr - zstart);

    // ---- weights (rewritten every call) ----
    p.w10 = (__bf16*)alloc(2048ull * K1P_ * 2);
    p.w11 = (__bf16*)alloc(2048ull * K1P_ * 2);
    p.w20 = (__bf16*)alloc(2048ull * K2P_ * 2);
    p.w21 = (__bf16*)alloc(2048ull * K2P_ * 2);
    p.wo  = (__bf16*)alloc(512ull * KOP_ * 2);
    p.wif0h = (__bf16*)alloc((size_t)IFP_ * 512 * 2);
    p.wif0l = (__bf16*)alloc((size_t)IFP_ * 512 * 2);
    p.wif1h = (__bf16*)alloc((size_t)IFP_ * 512 * 2);
    p.wif1l = (__bf16*)alloc((size_t)IFP_ * 512 * 2);
    for (int q = 0; q < 2; ++q) p.S0[q] = (float*)alloc((size_t)B_ * IFP_ * 4);
    for (int q = 0; q < 2; ++q) p.S1[q] = (float*)alloc((size_t)B_ * IFP_ * 4);

    hipMemsetAsync(zstart, 0, zbytes, stream);

    ConvArgs4 ca;
    ca.a[0] = { W_ih0,                 W_hh0,                 p.w10, NNIN_, H_, K1P_ };
    ca.a[1] = { W_ih0 + 2048ull*NNIN_, W_hh0 + 2048ull*H_,    p.w11, NNIN_, H_, K1P_ };
    ca.a[2] = { W_ih1,                 W_hh1,                 p.w20, H_,    H_, K2P_ };
    ca.a[3] = { W_ih1 + 2048ull*H_,    W_hh1 + 2048ull*H_,    p.w21, H_,    H_, K2P_ };
    conv_lstm<<<dim3((K1P_ + 255) / 256, 2048, 4), 256, 0, stream>>>(ca);

    conv_hi<<<dim3((KOP_ + 255) / 256, 512), 256, 0, stream>>>(
        W_out, NNIN_, nullptr, 0, 512, p.wo, KOP_);
    conv_hl<<<dim3(2, IFP_), 256, 0, stream>>>(
        W_iface, IFACE_, 512, p.wif0h, p.wif0l);
    conv_hl<<<dim3(2, IFP_), 256, 0, stream>>>(
        W_iface + (size_t)IFACE_ * 512, IFACE_, 512, p.wif1h, p.wif1l);
    build_inp<<<(B_ * IN_ + 255) / 256, 256, 0, stream>>>(x, p.a10h[0], p.a10l[0]);

    // 40 pipeline slots cover t=0..31 for all 9 stages
    for (int s = 0; s < T_ + 8; ++s) {
        slot_kernel<<<2048, 256, 0, stream>>>(p, s);
    }
}

// Round 8
// 940.376 us; speedup vs baseline: 1.5067x; 1.2319x over previous
//
#include <hip/hip_runtime.h>
#include <hip/hip_bf16.h>
#include <math.h>

#define B_ 128
#define T_ 32
#define IN_ 512
#define H_ 512
#define M_ 16
#define WC_ 20
#define R_ 4
#define RW_ 80
#define NNIN_ 592
#define IFACE_ 163
#define IFP_ 176
#define K1P_ 1120
#define K2P_ 1024
#define KOP_ 608
#define CLIP_ 20.0f
#define EPS_ 1e-6f
#define DELTA_ 5e-6f

typedef __bf16 bf16x8 __attribute__((ext_vector_type(8)));
typedef float f32x4 __attribute__((ext_vector_type(4)));

__device__ __forceinline__ float sigmoidf_(float x) { return 1.0f / (1.0f + __expf(-x)); }
__device__ __forceinline__ float tanhf_(float x) {
    float e = __expf(-2.f * fabsf(x));
    float t = (1.f - e) / (1.f + e);
    return copysignf(t, x);
}
__device__ __forceinline__ float softplusf_(float x) {
    return fmaxf(x, 0.0f) + log1pf(__expf(-fabsf(x)));
}
__device__ __forceinline__ void split2(float v, __bf16* hp, __bf16* lp) {
    __bf16 h = (__bf16)v;
    *hp = h;
    *lp = (__bf16)(v - (float)h);
}
#define WBAR_() __builtin_amdgcn_wave_barrier()

// ---------------------------------------------------------------------------
// Parameter block. LSTM/out weights: single bf16 limb. iface weights: 2-limb
// bf16 (hi+lo). Activations split hi/lo.
// ---------------------------------------------------------------------------
struct P {
    const float *x, *bih0, *bhh0, *bih1, *bhh1, *bif0, *bif1, *bout;
    float* out;
    __bf16 *a10h[4], *a10l[4];   // [x | 0 | h00], stride K1P
    __bf16 *a11h[4], *a11l[4];   // [out0 | rv0 | h10], stride K1P
    __bf16 *a20h[4], *a20l[4];   // [h0A | h01], stride K2P
    __bf16 *a21h[4], *a21l[4];   // [h1A | h11], stride K2P
    __bf16 *yh[4],  *yl[4];      // [out1 | rv1 | pad], stride KOP
    float *c00, *c01, *c10, *c11;
    float *mem0, *link0, *prec0, *rw0, *ww0, *us0;
    float *mem1, *link1, *prec1, *rw1, *ww1, *us1;
    __bf16 *w10, *w20, *w11, *w21, *wo;
    __bf16 *wif0h, *wif0l, *wif1h, *wif1l;   // [IFP_ x 512]
    float *S0[2], *S1[2];                    // [B_ x IFP_] activated iface
};

// ---------------------------------------------------------------------------
// mt-PAIRED fused LSTM GEMM tile: 32 batch rows x 16 hidden cols of all 4
// gates. Each W load (4 gates) feeds TWO A-tiles -> W traffic per output
// halves vs the single-mt tile. Per-output MFMA sequence identical (bit-
// identical results). 4 waves split K; all-wave LDS reduce + parallel
// epilogue, run twice (pair 0, pair 1). red = 16*256 floats (16 KB).
// ---------------------------------------------------------------------------
__device__ __forceinline__ void gemm_lstm_tile2(
    int tid, int jt, int mt0, float* red,
    const __bf16* Ah, const __bf16* Al, int KS,
    const __bf16* W, int nsteps,
    const float* b1, const float* b2, float* cst,
    __bf16* d1h, __bf16* d1l, int st1, int off1,
    __bf16* d2h, __bf16* d2l, int st2, int off2, int clip2)
{
    const int wave = tid >> 6, lane = tid & 63;
    const int l15 = lane & 15, quad = lane >> 4;
    const int j0 = jt * 16, m0 = mt0 * 16;

    f32x4 acc0[4], acc1[4];
    #pragma unroll
    for (int g = 0; g < 4; ++g)
        #pragma unroll
        for (int i = 0; i < 4; ++i) { acc0[g][i] = 0.f; acc1[g][i] = 0.f; }

    const int ks = (wave * nsteps) >> 2;
    const int ke = ((wave + 1) * nsteps) >> 2;

    size_t aoff0 = (size_t)(m0 + l15) * KS + ks * 32 + quad * 8;
    size_t aoff1 = aoff0 + (size_t)16 * KS;
    size_t woff[4];
    #pragma unroll
    for (int g = 0; g < 4; ++g)
        woff[g] = (size_t)(g * 512 + j0 + l15) * KS + ks * 32 + quad * 8;

    for (int s = ks; s < ke; ++s) {
        bf16x8 ah0 = *(const bf16x8*)(Ah + aoff0);
        bf16x8 al0 = *(const bf16x8*)(Al + aoff0);
        bf16x8 ah1 = *(const bf16x8*)(Ah + aoff1);
        bf16x8 al1 = *(const bf16x8*)(Al + aoff1);
        aoff0 += 32; aoff1 += 32;
        #pragma unroll
        for (int g = 0; g < 4; ++g) {
            bf16x8 wh = *(const bf16x8*)(W + woff[g]);
            woff[g] += 32;
            acc0[g] = __builtin_amdgcn_mfma_f32_16x16x32_bf16(ah0, wh, acc0[g], 0, 0, 0);
            acc0[g] = __builtin_amdgcn_mfma_f32_16x16x32_bf16(al0, wh, acc0[g], 0, 0, 0);
            acc1[g] = __builtin_amdgcn_mfma_f32_16x16x32_bf16(ah1, wh, acc1[g], 0, 0, 0);
            acc1[g] = __builtin_amdgcn_mfma_f32_16x16x32_bf16(al1, wh, acc1[g], 0, 0, 0);
        }
    }

    const int col = j0 + l15;
    float bg[4];
    #pragma unroll
    for (int g = 0; g < 4; ++g) bg[g] = b1[g * 512 + col] + b2[g * 512 + col];

    #pragma unroll
    for (int pair = 0; pair < 2; ++pair) {
        #pragma unroll
        for (int g = 0; g < 4; ++g)
            #pragma unroll
            for (int r = 0; r < 4; ++r)
                red[(g * 4 + r) * 256 + wave * 64 + lane] =
                    pair ? acc1[g][r] : acc0[g][r];
        __syncthreads();

        const int m = m0 + pair * 16 + quad * 4 + wave;
        float gv[4];
        #pragma unroll
        for (int g = 0; g < 4; ++g) {
            const float* rg = red + (g * 4 + wave) * 256;
            gv[g] = rg[lane] + rg[64 + lane] + rg[128 + lane] + rg[192 + lane] + bg[g];
        }
        float cold = cst[m * H_ + col];
        float cn = sigmoidf_(gv[1]) * cold + sigmoidf_(gv[0]) * tanhf_(gv[2]);
        cst[m * H_ + col] = cn;
        float h = sigmoidf_(gv[3]) * tanhf_(cn);
        split2(h, &d1h[(size_t)m * st1 + off1 + col], &d1l[(size_t)m * st1 + off1 + col]);
        float h2 = clip2 ? fminf(fmaxf(h, -CLIP_), CLIP_) : h;
        split2(h2, &d2h[(size_t)m * st2 + off2 + col], &d2l[(size_t)m * st2 + off2 + col]);
        if (pair == 0) __syncthreads();
    }
}

// ---------------------------------------------------------------------------
// Plain GEMM tile (out projection), W single-limb, all-wave epilogue.
// ---------------------------------------------------------------------------
__device__ __forceinline__ void gemm_plain_tile(
    int tid, int nt, int mt, float* red,
    const __bf16* Ah, const __bf16* Al, int AS,
    const __bf16* W, int WS,
    int nsteps, const float* bias, float* C, int ldc)
{
    const int wave = tid >> 6, lane = tid & 63;
    const int l15 = lane & 15, quad = lane >> 4;
    const int n0 = nt * 16, m0 = mt * 16;

    f32x4 acc;
    #pragma unroll
    for (int i = 0; i < 4; ++i) acc[i] = 0.f;

    const int ks = (wave * nsteps) >> 2;
    const int ke = ((wave + 1) * nsteps) >> 2;

    size_t aoff = (size_t)(m0 + l15) * AS + ks * 32 + quad * 8;
    size_t woff = (size_t)(n0 + l15) * WS + ks * 32 + quad * 8;

    for (int s = ks; s < ke; ++s) {
        bf16x8 ah = *(const bf16x8*)(Ah + aoff);
        bf16x8 al = *(const bf16x8*)(Al + aoff);
        bf16x8 wh = *(const bf16x8*)(W + woff);
        aoff += 32; woff += 32;
        acc = __builtin_amdgcn_mfma_f32_16x16x32_bf16(ah, wh, acc, 0, 0, 0);
        acc = __builtin_amdgcn_mfma_f32_16x16x32_bf16(al, wh, acc, 0, 0, 0);
    }

    #pragma unroll
    for (int r = 0; r < 4; ++r) red[r * 256 + wave * 64 + lane] = acc[r];
    __syncthreads();

    const int col = n0 + l15;
    const int m = m0 + quad * 4 + wave;
    const float* rg = red + wave * 256;
    float v = rg[lane] + rg[64 + lane] + rg[128 + lane] + rg[192 + lane] + bias[col];
    C[(size_t)m * ldc + col] = v;
}

// ---------------------------------------------------------------------------
// iface GEMM tile: S = act(out @ Wif^T + bif). A 2-limb x W 2-limb, 3 MFMAs
// per K-step (al*wl dropped). K = 512 fixed -> 16 steps, 4 per wave.
// ---------------------------------------------------------------------------
__device__ __forceinline__ void gemm_iface_tile(
    int tid, int jt, int mt, float* red,
    const __bf16* Ah, const __bf16* Al, int AS,
    const __bf16* Wh, const __bf16* Wl,
    const float* bif, float* Sout)
{
    const int wave = tid >> 6, lane = tid & 63;
    const int l15 = lane & 15, quad = lane >> 4;
    const int n0 = jt * 16, m0 = mt * 16;

    f32x4 acc;
    #pragma unroll
    for (int i = 0; i < 4; ++i) acc[i] = 0.f;

    size_t aoff = (size_t)(m0 + l15) * AS + wave * 128 + quad * 8;
    size_t woff = (size_t)(n0 + l15) * 512 + wave * 128 + quad * 8;

    #pragma unroll
    for (int s = 0; s < 4; ++s) {
        bf16x8 ah = *(const bf16x8*)(Ah + aoff);
        bf16x8 al = *(const bf16x8*)(Al + aoff);
        bf16x8 wh = *(const bf16x8*)(Wh + woff);
        bf16x8 wl = *(const bf16x8*)(Wl + woff);
        aoff += 32; woff += 32;
        acc = __builtin_amdgcn_mfma_f32_16x16x32_bf16(ah, wh, acc, 0, 0, 0);
        acc = __builtin_amdgcn_mfma_f32_16x16x32_bf16(al, wh, acc, 0, 0, 0);
        acc = __builtin_amdgcn_mfma_f32_16x16x32_bf16(ah, wl, acc, 0, 0, 0);
    }

    #pragma unroll
    for (int r = 0; r < 4; ++r) red[r * 256 + wave * 64 + lane] = acc[r];
    __syncthreads();

    const int o = n0 + l15;
    if (o < IFACE_) {
        const int m = m0 + quad * 4 + wave;
        const float* rg = red + wave * 256;
        float v = rg[lane] + rg[64 + lane] + rg[128 + lane] + rg[192 + lane] + bif[o];
        float rr;
        if (o < 80)        rr = tanhf_(v);
        else if (o < 84)   rr = softplusf_(v);
        else if (o < 104)  rr = tanhf_(v);
        else if (o < 105)  rr = softplusf_(v);
        else if (o < 125)  rr = sigmoidf_(v);
        else if (o < 145)  rr = tanhf_(v);
        else if (o < 151)  rr = sigmoidf_(v);
        else               rr = v;
        Sout[(size_t)m * IFP_ + o] = rr;
    }
}

// ---------------------------------------------------------------------------
// DNC memory step, WAVE-SYNCHRONOUS: one wave per batch element, no
// __syncthreads (zero-cost wave_barrier compiler fences at phase edges).
// Per-wave LDS scratch region W[1024] layout:
//   [0,163)   sif          [164,176) modes      [208,224) wwnew
//   [224,240) precold      [240,304) rwold      [304,368) rwnew
//   [368,624) lnk          [624,944) memS
// Arithmetic is copied verbatim from the previous block-wide version.
// ---------------------------------------------------------------------------
__device__ void mem_batch(int b, int wl, float* W, const float* Sbuf,
    float* mem, float* link, float* prec, float* rw,
    float* ww, float* usage, __bf16* rvh, __bf16* rvl, int rvst)
{
    // ---- load S + state ----
    for (int i = wl; i < IFACE_; i += 64) W[i] = Sbuf[(size_t)b * IFP_ + i];
    if (wl < M_) W[224 + wl] = prec[(size_t)b * M_ + wl];
    W[240 + wl] = rw[(size_t)b * R_ * M_ + wl];
    #pragma unroll
    for (int k = 0; k < 4; ++k)
        W[368 + wl + 64 * k] = link[(size_t)b * M_ * M_ + wl + 64 * k];
    #pragma unroll
    for (int k = 0; k < 5; ++k)
        W[624 + wl + 64 * k] = mem[(size_t)b * M_ * WC_ + wl + 64 * k];
    WBAR_();

    // ---- read-mode softmax (lanes 0..3) ----
    if (wl < R_) {
        float a0 = W[151 + wl * 3], a1 = W[152 + wl * 3], a2 = W[153 + wl * 3];
        float mx = fmaxf(a0, fmaxf(a1, a2));
        float e0 = __expf(a0 - mx), e1 = __expf(a1 - mx), e2 = __expf(a2 - mx);
        float s = e0 + e1 + e2;
        W[164 + wl * 3] = e0 / s; W[165 + wl * 3] = e1 / s; W[166 + wl * 3] = e2 / s;
    }
    WBAR_();

    // ---- usage / write-weights / precedence (lanes 0..15) ----
    if (wl < M_) {
        const int m = wl;
        float wwold = ww[(size_t)b * M_ + m];
        float u = usage[(size_t)b * M_ + m];
        u = u + (1.f - u) * wwold;
        float psi = 1.f;
        #pragma unroll
        for (int r = 0; r < R_; ++r) psi *= (1.f - W[145 + r] * W[240 + r * 16 + m]);
        u *= psi;

        float kn2 = 0.f, mn2 = 0.f, dot = 0.f;
        #pragma unroll
        for (int w = 0; w < WC_; ++w) {
            float kv = W[84 + w], mv = W[624 + m * WC_ + w];
            kn2 += kv * kv; mn2 += mv * mv; dot += kv * mv;
        }
        float c = dot / ((sqrtf(kn2) + EPS_) * (sqrtf(mn2) + EPS_)) * W[104];
        float mx = c;
        #pragma unroll
        for (int off = 8; off; off >>= 1) mx = fmaxf(mx, __shfl_xor(mx, off, 16));
        float e = __expf(c - mx);
        float se = e;
        #pragma unroll
        for (int off = 8; off; off >>= 1) se += __shfl_xor(se, off, 16);
        float wcw = e / se;

        float uu = DELTA_ + (1.f - DELTA_) * u;
        int rank = 0;
        #pragma unroll
        for (int j = 0; j < 16; ++j) {
            float uj = __shfl(uu, j, 16);
            if (uj < uu || (uj == uu && j < m)) ++rank;
        }
        float prod = 1.f;
        #pragma unroll
        for (int j = 0; j < 16; ++j) {
            float uj = __shfl(uu, j, 16);
            int   rj = __shfl(rank, j, 16);
            if (rj < rank) prod *= uj;
        }
        float alloc = (1.f - uu) * prod;

        float ag = W[149], wg = W[150];
        float wwn = wg * (ag * alloc + (1.f - ag) * wcw);
        float sw = wwn;
        #pragma unroll
        for (int off = 8; off; off >>= 1) sw += __shfl_xor(sw, off, 16);

        W[208 + m] = wwn;
        usage[(size_t)b * M_ + m] = u;
        ww[(size_t)b * M_ + m]    = wwn;
        prec[(size_t)b * M_ + m]  = (1.f - sw) * W[224 + m] + wwn;
    }
    WBAR_();

    // ---- memory + link update ----
    #pragma unroll
    for (int k = 0; k < 5; ++k) {
        int i = wl + 64 * k;
        int m = i / WC_, w = i - m * WC_;
        float nm = W[624 + i] * (1.f - W[208 + m] * W[105 + w]) + W[208 + m] * W[125 + w];
        W[624 + i] = nm;
        mem[(size_t)b * M_ * WC_ + i] = nm;
    }
    #pragma unroll
    for (int k = 0; k < 4; ++k) {
        int i = wl + 64 * k;
        int ii = i >> 4, jj = i & 15;
        float v = (1.f - W[208 + ii] - W[208 + jj]) * W[368 + i] + W[208 + ii] * W[224 + jj];
        if (ii == jj) v = 0.f;
        W[368 + i] = v;
        link[(size_t)b * M_ * M_ + i] = v;
    }
    WBAR_();

    // ---- read content weights + softmax + temporal mix (64 lanes) ----
    {
        const int r = wl >> 4, m = wl & 15;
        float kn2 = 0.f, mn2 = 0.f, dot = 0.f;
        #pragma unroll
        for (int w = 0; w < WC_; ++w) {
            float kv = W[r * WC_ + w], mv = W[624 + m * WC_ + w];
            kn2 += kv * kv; mn2 += mv * mv; dot += kv * mv;
        }
        float c = dot / ((sqrtf(kn2) + EPS_) * (sqrtf(mn2) + EPS_)) * W[80 + r];
        float mx = c;
        #pragma unroll
        for (int off = 8; off; off >>= 1) mx = fmaxf(mx, __shfl_xor(mx, off, 16));
        float e = __expf(c - mx);
        float se = e;
        #pragma unroll
        for (int off = 8; off; off >>= 1) se += __shfl_xor(se, off, 16);
        float rc = e / se;

        float fwd = 0.f, bwd = 0.f;
        #pragma unroll
        for (int j = 0; j < M_; ++j) fwd += W[368 + m * 16 + j] * W[240 + r * 16 + j];
        #pragma unroll
        for (int i2 = 0; i2 < M_; ++i2) bwd += W[240 + r * 16 + i2] * W[368 + i2 * 16 + m];
        float v = W[164 + r * 3 + 0] * bwd + W[164 + r * 3 + 1] * fwd + W[164 + r * 3 + 2] * rc;
        W[304 + wl] = v;
        rw[(size_t)b * R_ * M_ + wl] = v;
    }
    WBAR_();

    // ---- read vectors (80 outputs: lane i, plus lanes 0..15 do i+64) ----
    #pragma unroll
    for (int k = 0; k < 2; ++k) {
        int i = wl + 64 * k;
        if (i < RW_) {
            int r = i / WC_, w = i - r * WC_;
            float s = 0.f;
            #pragma unroll
            for (int m = 0; m < M_; ++m) s += W[304 + r * 16 + m] * W[624 + m * WC_ + w];
            split2(s, &rvh[(size_t)b * rvst + IN_ + i], &rvl[(size_t)b * rvst + IN_ + i]);
        }
    }
}

// 4 batches per block, one wave each (no block-wide barriers in the mem path).
__device__ void mem_group4(int bbase, int tid, float* smem, const float* Sbuf,
    float* mem, float* link, float* prec, float* rw, float* ww, float* usage,
    __bf16* rvh, __bf16* rvl, int rvst)
{
    const int wave = tid >> 6, wl = tid & 63;
    mem_batch(bbase + wave, wl, smem + wave * 1024, Sbuf,
              mem, link, prec, rw, ww, usage, rvh, rvl, rvst);
}

// ---------------------------------------------------------------------------
// One pipeline slot (1040 blocks; M first so tail chains start at dispatch).
//   [0,32):       M0(t=s-3)   32 blocks x 4 batches
//   [32,64):      M1(t=s-7)   32 blocks x 4 batches
//   [64,192):     A0(t=s)     128 blocks (jt 32 x mt-pair 4)
//   [192,320):    B0(t=s-1)
//   [320,448):    A1(t=s-4)
//   [448,576):    B1(t=s-5)
//   [576,832):    Y(t=s-8)    256 blocks
//   [832,920):    IF0(t=s-2)  88 blocks
//   [920,1008):   IF1(t=s-6)  88 blocks
//   [1008,1040):  x(s+1) convert
// ---------------------------------------------------------------------------
__global__ __launch_bounds__(256, 6) void slot_kernel(P p, int s)
{
    __shared__ float smem[4096];
    const int blk = blockIdx.x, tid = threadIdx.x;

    if (blk < 32) {                        // M0(t=s-3)
        int t = s - 3;
        if (t >= 0 && t < T_) {
            mem_group4(blk * 4, tid, smem, p.S0[t & 1],
                p.mem0, p.link0, p.prec0, p.rw0, p.ww0, p.us0,
                p.a11h[t & 3], p.a11l[t & 3], K1P_);
        }
    } else if (blk < 64) {                 // M1(t=s-7)
        int t = s - 7;
        if (t >= 0 && t < T_) {
            mem_group4((blk - 32) * 4, tid, smem, p.S1[t & 1],
                p.mem1, p.link1, p.prec1, p.rw1, p.ww1, p.us1,
                p.yh[t & 3], p.yl[t & 3], KOP_);
        }
    } else if (blk < 192) {                // A0(t=s)
        int t = s;
        if (t < T_) {
            int k = blk - 64;
            gemm_lstm_tile2(tid, k & 31, (k >> 5) * 2, smem,
                p.a10h[t & 3], p.a10l[t & 3], K1P_, p.w10, K1P_ / 32,
                p.bih0, p.bhh0, p.c00,
                p.a10h[(t + 1) & 3], p.a10l[(t + 1) & 3], K1P_, NNIN_,
                p.a20h[t & 3], p.a20l[t & 3], K2P_, 0, 0);
        }
    } else if (blk < 320) {                // B0(t=s-1)
        int t = s - 1;
        if (t >= 0 && t < T_) {
            int k = blk - 192;
            gemm_lstm_tile2(tid, k & 31, (k >> 5) * 2, smem,
                p.a20h[t & 3], p.a20l[t & 3], K2P_, p.w20, K2P_ / 32,
                p.bih1, p.bhh1, p.c01,
                p.a20h[(t + 1) & 3], p.a20l[(t + 1) & 3], K2P_, H_,
                p.a11h[t & 3], p.a11l[t & 3], K1P_, 0, 1);
        }
    } else if (blk < 448) {                // A1(t=s-4)
        int t = s - 4;
        if (t >= 0 && t < T_) {
            int k = blk - 320;
            gemm_lstm_tile2(tid, k & 31, (k >> 5) * 2, smem,
                p.a11h[t & 3], p.a11l[t & 3], K1P_, p.w11, K1P_ / 32,
                p.bih0 + 2048, p.bhh0 + 2048, p.c10,
                p.a11h[(t + 1) & 3], p.a11l[(t + 1) & 3], K1P_, NNIN_,
                p.a21h[t & 3], p.a21l[t & 3], K2P_, 0, 0);
        }
    } else if (blk < 576) {                // B1(t=s-5)
        int t = s - 5;
        if (t >= 0 && t < T_) {
            int k = blk - 448;
            gemm_lstm_tile2(tid, k & 31, (k >> 5) * 2, smem,
                p.a21h[t & 3], p.a21l[t & 3], K2P_, p.w21, K2P_ / 32,
                p.bih1 + 2048, p.bhh1 + 2048, p.c11,
                p.a21h[(t + 1) & 3], p.a21l[(t + 1) & 3], K2P_, H_,
                p.yh[t & 3], p.yl[t & 3], KOP_, 0, 1);
        }
    } else if (blk < 832) {                // Y(t=s-8)
        int t = s - 8;
        if (t >= 0 && t < T_) {
            int tile = blk - 576;
            gemm_plain_tile(tid, tile & 31, tile >> 5, smem,
                p.yh[t & 3], p.yl[t & 3], KOP_, p.wo, KOP_, KOP_ / 32,
                p.bout, p.out + (size_t)t * IN_, T_ * IN_);
        }
    } else if (blk < 920) {                // IF0(t=s-2)
        int t = s - 2;
        if (t >= 0 && t < T_) {
            int b2 = blk - 832;
            gemm_iface_tile(tid, b2 % 11, b2 / 11, smem,
                p.a11h[t & 3], p.a11l[t & 3], K1P_,
                p.wif0h, p.wif0l, p.bif0, p.S0[t & 1]);
        }
    } else if (blk < 1008) {               // IF1(t=s-6)
        int t = s - 6;
        if (t >= 0 && t < T_) {
            int b2 = blk - 920;
            gemm_iface_tile(tid, b2 % 11, b2 / 11, smem,
                p.yh[t & 3], p.yl[t & 3], KOP_,
                p.wif1h, p.wif1l, p.bif1, p.S1[t & 1]);
        }
    } else {                               // x(s+1) convert
        int tn = s + 1;
        if (tn < T_) {
            for (int i = (blk - 1008) * 256 + tid; i < B_ * IN_; i += 32 * 256) {
                int b = i >> 9, j = i & 511;
                float v = p.x[((size_t)b * T_ + tn) * IN_ + j];
                split2(v, &p.a10h[tn & 3][(size_t)b * K1P_ + j],
                          &p.a10l[tn & 3][(size_t)b * K1P_ + j]);
            }
        }
    }
}

// ---------------------------------------------------------------------------
// Setup kernels
// ---------------------------------------------------------------------------
struct ConvArgs { const float* s1; const float* s2; __bf16* dst; int K1, K2, Kd; };
struct ConvArgs4 { ConvArgs a[4]; };

__global__ __launch_bounds__(256) void conv_lstm(ConvArgs4 ca)
{
    ConvArgs c = ca.a[blockIdx.z];
    int k = blockIdx.x * 256 + threadIdx.x;
    if (k >= c.Kd) return;
    int n = blockIdx.y;
    float v = 0.f;
    if (k < c.K1) v = c.s1[(size_t)n * c.K1 + k];
    else if (k < c.K1 + c.K2) v = c.s2[(size_t)n * c.K2 + (k - c.K1)];
    c.dst[(size_t)n * c.Kd + k] = (__bf16)v;
}

__global__ __launch_bounds__(256) void conv_hi(
    const float* __restrict__ s1, int K1, const float* __restrict__ s2, int K2,
    int Nsrc, __bf16* __restrict__ hi, int Kd)
{
    int k = blockIdx.x * 256 + threadIdx.x;
    int n = blockIdx.y;
    if (k >= Kd) return;
    float v = 0.f;
    if (n < Nsrc) {
        if (k < K1) v = s1[(size_t)n * K1 + k];
        else if (k < K1 + K2) v = s2[(size_t)n * K2 + (k - K1)];
    }
    hi[(size_t)n * Kd + k] = (__bf16)v;
}

__global__ __launch_bounds__(256) void conv_hl(
    const float* __restrict__ src, int Nsrc, int K,
    __bf16* __restrict__ hi, __bf16* __restrict__ lo)
{
    int k = blockIdx.x * 256 + threadIdx.x;
    int n = blockIdx.y;
    if (k >= K) return;
    float v = (n < Nsrc) ? src[(size_t)n * K + k] : 0.f;
    split2(v, &hi[(size_t)n * K + k], &lo[(size_t)n * K + k]);
}

__global__ __launch_bounds__(256) void build_inp(const float* __restrict__ x,
                                                 __bf16* __restrict__ a1h,
                                                 __bf16* __restrict__ a1l)
{
    int idx = blockIdx.x * 256 + threadIdx.x;
    if (idx >= B_ * IN_) return;
    int b = idx >> 9, j = idx & 511;
    float v = x[(size_t)b * T_ * IN_ + j];
    split2(v, &a1h[b * K1P_ + j], &a1l[b * K1P_ + j]);
}

// ---------------------------------------------------------------------------
extern "C" void kernel_launch(void* const* d_in, const int* in_sizes, int n_in,
                              void* d_out, int out_size, void* d_ws, size_t ws_size,
                              hipStream_t stream)
{
    const float* x       = (const float*)d_in[0];
    const float* W_ih0   = (const float*)d_in[1];
    const float* W_hh0   = (const float*)d_in[2];
    const float* b_ih0   = (const float*)d_in[3];
    const float* b_hh0   = (const float*)d_in[4];
    const float* W_ih1   = (const float*)d_in[5];
    const float* W_hh1   = (const float*)d_in[6];
    const float* b_ih1   = (const float*)d_in[7];
    const float* b_hh1   = (const float*)d_in[8];
    const float* W_iface = (const float*)d_in[9];
    const float* b_iface = (const float*)d_in[10];
    const float* W_out   = (const float*)d_in[11];
    const float* b_out   = (const float*)d_in[12];

    P p;
    p.x = x;
    p.bih0 = b_ih0; p.bhh0 = b_hh0; p.bih1 = b_ih1; p.bhh1 = b_hh1;
    p.bif0 = b_iface; p.bif1 = b_iface + IFACE_;
    p.bout = b_out;
    p.out = (float*)d_out;

    char* ptr = (char*)d_ws;
    auto alloc = [&](size_t bytes) { char* r = ptr; ptr += (bytes + 255) & ~(size_t)255; return r; };

    // ---- zero zone (memset each call) ----
    char* zstart = ptr;
    for (int q = 0; q < 4; ++q) { p.a10h[q] = (__bf16*)alloc(B_ * K1P_ * 2); p.a10l[q] = (__bf16*)alloc(B_ * K1P_ * 2); }
    for (int q = 0; q < 4; ++q) { p.a11h[q] = (__bf16*)alloc(B_ * K1P_ * 2); p.a11l[q] = (__bf16*)alloc(B_ * K1P_ * 2); }
    for (int q = 0; q < 4; ++q) { p.a20h[q] = (__bf16*)alloc(B_ * K2P_ * 2); p.a20l[q] = (__bf16*)alloc(B_ * K2P_ * 2); }
    for (int q = 0; q < 4; ++q) { p.a21h[q] = (__bf16*)alloc(B_ * K2P_ * 2); p.a21l[q] = (__bf16*)alloc(B_ * K2P_ * 2); }
    for (int q = 0; q < 4; ++q) { p.yh[q]  = (__bf16*)alloc(B_ * KOP_ * 2);  p.yl[q]  = (__bf16*)alloc(B_ * KOP_ * 2); }
    p.c00 = (float*)alloc((size_t)B_ * H_ * 4);
    p.c01 = (float*)alloc((size_t)B_ * H_ * 4);
    p.c10 = (float*)alloc((size_t)B_ * H_ * 4);
    p.c11 = (float*)alloc((size_t)B_ * H_ * 4);
    p.mem0  = (float*)alloc((size_t)B_ * M_ * WC_ * 4);
    p.link0 = (float*)alloc((size_t)B_ * M_ * M_ * 4);
    p.prec0 = (float*)alloc((size_t)B_ * M_ * 4);
    p.rw0   = (float*)alloc((size_t)B_ * R_ * M_ * 4);
    p.ww0   = (float*)alloc((size_t)B_ * M_ * 4);
    p.us0   = (float*)alloc((size_t)B_ * M_ * 4);
    p.mem1  = (float*)alloc((size_t)B_ * M_ * WC_ * 4);
    p.link1 = (float*)alloc((size_t)B_ * M_ * M_ * 4);
    p.prec1 = (float*)alloc((size_t)B_ * M_ * 4);
    p.rw1   = (float*)alloc((size_t)B_ * R_ * M_ * 4);
    p.ww1   = (float*)alloc((size_t)B_ * M_ * 4);
    p.us1   = (float*)alloc((size_t)B_ * M_ * 4);
    size_t zbytes = (size_t)(ptr - zstart);

    // ---- weights (rewritten every call) ----
    p.w10 = (__bf16*)alloc(2048ull * K1P_ * 2);
    p.w11 = (__bf16*)alloc(2048ull * K1P_ * 2);
    p.w20 = (__bf16*)alloc(2048ull * K2P_ * 2);
    p.w21 = (__bf16*)alloc(2048ull * K2P_ * 2);
    p.wo  = (__bf16*)alloc(512ull * KOP_ * 2);
    p.wif0h = (__bf16*)alloc((size_t)IFP_ * 512 * 2);
    p.wif0l = (__bf16*)alloc((size_t)IFP_ * 512 * 2);
    p.wif1h = (__bf16*)alloc((size_t)IFP_ * 512 * 2);
    p.wif1l = (__bf16*)alloc((size_t)IFP_ * 512 * 2);
    for (int q = 0; q < 2; ++q) p.S0[q] = (float*)alloc((size_t)B_ * IFP_ * 4);
    for (int q = 0; q < 2; ++q) p.S1[q] = (float*)alloc((size_t)B_ * IFP_ * 4);

    hipMemsetAsync(zstart, 0, zbytes, stream);

    ConvArgs4 ca;
    ca.a[0] = { W_ih0,                 W_hh0,                 p.w10, NNIN_, H_, K1P_ };
    ca.a[1] = { W_ih0 + 2048ull*NNIN_, W_hh0 + 2048ull*H_,    p.w11, NNIN_, H_, K1P_ };
    ca.a[2] = { W_ih1,                 W_hh1,                 p.w20, H_,    H_, K2P_ };
    ca.a[3] = { W_ih1 + 2048ull*H_,    W_hh1 + 2048ull*H_,    p.w21, H_,    H_, K2P_ };
    conv_lstm<<<dim3((K1P_ + 255) / 256, 2048, 4), 256, 0, stream>>>(ca);

    conv_hi<<<dim3((KOP_ + 255) / 256, 512), 256, 0, stream>>>(
        W_out, NNIN_, nullptr, 0, 512, p.wo, KOP_);
    conv_hl<<<dim3(2, IFP_), 256, 0, stream>>>(
        W_iface, IFACE_, 512, p.wif0h, p.wif0l);
    conv_hl<<<dim3(2, IFP_), 256, 0, stream>>>(
        W_iface + (size_t)IFACE_ * 512, IFACE_, 512, p.wif1h, p.wif1l);
    build_inp<<<(B_ * IN_ + 255) / 256, 256, 0, stream>>>(x, p.a10h[0], p.a10l[0]);

    // 40 pipeline slots cover t=0..31 for all 9 stages
    for (int s = 0; s < T_ + 8; ++s) {
        slot_kernel<<<1040, 256, 0, stream>>>(p, s);
    }
}

// Round 9
// 902.929 us; speedup vs baseline: 1.5692x; 1.0415x over previous
//
#include <hip/hip_runtime.h>
#include <hip/hip_bf16.h>
#include <math.h>

#define B_ 128
#define T_ 32
#define IN_ 512
#define H_ 512
#define M_ 16
#define WC_ 20
#define R_ 4
#define RW_ 80
#define NNIN_ 592
#define IFACE_ 163
#define IFP_ 176
#define K1P_ 1120
#define K2P_ 1024
#define KOP_ 608
#define CLIP_ 20.0f
#define EPS_ 1e-6f
#define DELTA_ 5e-6f

typedef __bf16 bf16x8 __attribute__((ext_vector_type(8)));
typedef float f32x4 __attribute__((ext_vector_type(4)));

__device__ __forceinline__ float sigmoidf_(float x) { return 1.0f / (1.0f + __expf(-x)); }
__device__ __forceinline__ float tanhf_(float x) {
    float e = __expf(-2.f * fabsf(x));
    float t = (1.f - e) / (1.f + e);
    return copysignf(t, x);
}
__device__ __forceinline__ float softplusf_(float x) {
    return fmaxf(x, 0.0f) + log1pf(__expf(-fabsf(x)));
}
__device__ __forceinline__ void split2(float v, __bf16* hp, __bf16* lp) {
    __bf16 h = (__bf16)v;
    *hp = h;
    *lp = (__bf16)(v - (float)h);
}
#define WBAR_() __builtin_amdgcn_wave_barrier()

// ---------------------------------------------------------------------------
// Parameter block. LSTM/out weights: single bf16 limb. iface weights: 2-limb
// bf16 (hi+lo). Activations split hi/lo.
// ---------------------------------------------------------------------------
struct P {
    const float *x, *bih0, *bhh0, *bih1, *bhh1, *bif0, *bif1, *bout;
    float* out;
    __bf16 *a10h[4], *a10l[4];   // [x | 0 | h00], stride K1P
    __bf16 *a11h[4], *a11l[4];   // [out0 | rv0 | h10], stride K1P
    __bf16 *a20h[4], *a20l[4];   // [h0A | h01], stride K2P
    __bf16 *a21h[4], *a21l[4];   // [h1A | h11], stride K2P
    __bf16 *yh[4],  *yl[4];      // [out1 | rv1 | pad], stride KOP
    float *c00, *c01, *c10, *c11;
    float *mem0, *link0, *prec0, *rw0, *ww0, *us0;
    float *mem1, *link1, *prec1, *rw1, *ww1, *us1;
    __bf16 *w10, *w20, *w11, *w21, *wo;
    __bf16 *wif0h, *wif0l, *wif1h, *wif1l;   // [IFP_ x 512]
    float *S0[2], *S1[2];                    // [B_ x IFP_] activated iface
};

// ---------------------------------------------------------------------------
// mt-PAIRED fused LSTM GEMM tile: 32 batch rows x 16 hidden cols of all 4
// gates. Each W load feeds TWO A-tiles. 4 waves split K; all-wave LDS reduce
// + parallel epilogue, run twice. red = 16*256 floats (16 KB).
// ---------------------------------------------------------------------------
__device__ __forceinline__ void gemm_lstm_tile2(
    int tid, int jt, int mt0, float* red,
    const __bf16* Ah, const __bf16* Al, int KS,
    const __bf16* W, int nsteps,
    const float* b1, const float* b2, float* cst,
    __bf16* d1h, __bf16* d1l, int st1, int off1,
    __bf16* d2h, __bf16* d2l, int st2, int off2, int clip2)
{
    const int wave = tid >> 6, lane = tid & 63;
    const int l15 = lane & 15, quad = lane >> 4;
    const int j0 = jt * 16, m0 = mt0 * 16;

    f32x4 acc0[4], acc1[4];
    #pragma unroll
    for (int g = 0; g < 4; ++g)
        #pragma unroll
        for (int i = 0; i < 4; ++i) { acc0[g][i] = 0.f; acc1[g][i] = 0.f; }

    const int ks = (wave * nsteps) >> 2;
    const int ke = ((wave + 1) * nsteps) >> 2;

    size_t aoff0 = (size_t)(m0 + l15) * KS + ks * 32 + quad * 8;
    size_t aoff1 = aoff0 + (size_t)16 * KS;
    size_t woff[4];
    #pragma unroll
    for (int g = 0; g < 4; ++g)
        woff[g] = (size_t)(g * 512 + j0 + l15) * KS + ks * 32 + quad * 8;

    for (int s = ks; s < ke; ++s) {
        bf16x8 ah0 = *(const bf16x8*)(Ah + aoff0);
        bf16x8 al0 = *(const bf16x8*)(Al + aoff0);
        bf16x8 ah1 = *(const bf16x8*)(Ah + aoff1);
        bf16x8 al1 = *(const bf16x8*)(Al + aoff1);
        aoff0 += 32; aoff1 += 32;
        #pragma unroll
        for (int g = 0; g < 4; ++g) {
            bf16x8 wh = *(const bf16x8*)(W + woff[g]);
            woff[g] += 32;
            acc0[g] = __builtin_amdgcn_mfma_f32_16x16x32_bf16(ah0, wh, acc0[g], 0, 0, 0);
            acc0[g] = __builtin_amdgcn_mfma_f32_16x16x32_bf16(al0, wh, acc0[g], 0, 0, 0);
            acc1[g] = __builtin_amdgcn_mfma_f32_16x16x32_bf16(ah1, wh, acc1[g], 0, 0, 0);
            acc1[g] = __builtin_amdgcn_mfma_f32_16x16x32_bf16(al1, wh, acc1[g], 0, 0, 0);
        }
    }

    const int col = j0 + l15;
    float bg[4];
    #pragma unroll
    for (int g = 0; g < 4; ++g) bg[g] = b1[g * 512 + col] + b2[g * 512 + col];

    #pragma unroll
    for (int pair = 0; pair < 2; ++pair) {
        #pragma unroll
        for (int g = 0; g < 4; ++g)
            #pragma unroll
            for (int r = 0; r < 4; ++r)
                red[(g * 4 + r) * 256 + wave * 64 + lane] =
                    pair ? acc1[g][r] : acc0[g][r];
        __syncthreads();

        const int m = m0 + pair * 16 + quad * 4 + wave;
        float gv[4];
        #pragma unroll
        for (int g = 0; g < 4; ++g) {
            const float* rg = red + (g * 4 + wave) * 256;
            gv[g] = rg[lane] + rg[64 + lane] + rg[128 + lane] + rg[192 + lane] + bg[g];
        }
        float cold = cst[m * H_ + col];
        float cn = sigmoidf_(gv[1]) * cold + sigmoidf_(gv[0]) * tanhf_(gv[2]);
        cst[m * H_ + col] = cn;
        float h = sigmoidf_(gv[3]) * tanhf_(cn);
        split2(h, &d1h[(size_t)m * st1 + off1 + col], &d1l[(size_t)m * st1 + off1 + col]);
        float h2 = clip2 ? fminf(fmaxf(h, -CLIP_), CLIP_) : h;
        split2(h2, &d2h[(size_t)m * st2 + off2 + col], &d2l[(size_t)m * st2 + off2 + col]);
        if (pair == 0) __syncthreads();
    }
}

// ---------------------------------------------------------------------------
// Plain GEMM tile (out projection), W single-limb, all-wave epilogue.
// ---------------------------------------------------------------------------
__device__ __forceinline__ void gemm_plain_tile(
    int tid, int nt, int mt, float* red,
    const __bf16* Ah, const __bf16* Al, int AS,
    const __bf16* W, int WS,
    int nsteps, const float* bias, float* C, int ldc)
{
    const int wave = tid >> 6, lane = tid & 63;
    const int l15 = lane & 15, quad = lane >> 4;
    const int n0 = nt * 16, m0 = mt * 16;

    f32x4 acc;
    #pragma unroll
    for (int i = 0; i < 4; ++i) acc[i] = 0.f;

    const int ks = (wave * nsteps) >> 2;
    const int ke = ((wave + 1) * nsteps) >> 2;

    size_t aoff = (size_t)(m0 + l15) * AS + ks * 32 + quad * 8;
    size_t woff = (size_t)(n0 + l15) * WS + ks * 32 + quad * 8;

    for (int s = ks; s < ke; ++s) {
        bf16x8 ah = *(const bf16x8*)(Ah + aoff);
        bf16x8 al = *(const bf16x8*)(Al + aoff);
        bf16x8 wh = *(const bf16x8*)(W + woff);
        aoff += 32; woff += 32;
        acc = __builtin_amdgcn_mfma_f32_16x16x32_bf16(ah, wh, acc, 0, 0, 0);
        acc = __builtin_amdgcn_mfma_f32_16x16x32_bf16(al, wh, acc, 0, 0, 0);
    }

    #pragma unroll
    for (int r = 0; r < 4; ++r) red[r * 256 + wave * 64 + lane] = acc[r];
    __syncthreads();

    const int col = n0 + l15;
    const int m = m0 + quad * 4 + wave;
    const float* rg = red + wave * 256;
    float v = rg[lane] + rg[64 + lane] + rg[128 + lane] + rg[192 + lane] + bias[col];
    C[(size_t)m * ldc + col] = v;
}

// ---------------------------------------------------------------------------
// iface GEMM tile: S = act(out @ Wif^T + bif). A 2-limb x W 2-limb, 3 MFMAs
// per K-step (al*wl dropped). K = 512 fixed -> 16 steps, 4 per wave.
// ---------------------------------------------------------------------------
__device__ __forceinline__ void gemm_iface_tile(
    int tid, int jt, int mt, float* red,
    const __bf16* Ah, const __bf16* Al, int AS,
    const __bf16* Wh, const __bf16* Wl,
    const float* bif, float* Sout)
{
    const int wave = tid >> 6, lane = tid & 63;
    const int l15 = lane & 15, quad = lane >> 4;
    const int n0 = jt * 16, m0 = mt * 16;

    f32x4 acc;
    #pragma unroll
    for (int i = 0; i < 4; ++i) acc[i] = 0.f;

    size_t aoff = (size_t)(m0 + l15) * AS + wave * 128 + quad * 8;
    size_t woff = (size_t)(n0 + l15) * 512 + wave * 128 + quad * 8;

    #pragma unroll
    for (int s = 0; s < 4; ++s) {
        bf16x8 ah = *(const bf16x8*)(Ah + aoff);
        bf16x8 al = *(const bf16x8*)(Al + aoff);
        bf16x8 wh = *(const bf16x8*)(Wh + woff);
        bf16x8 wl = *(const bf16x8*)(Wl + woff);
        aoff += 32; woff += 32;
        acc = __builtin_amdgcn_mfma_f32_16x16x32_bf16(ah, wh, acc, 0, 0, 0);
        acc = __builtin_amdgcn_mfma_f32_16x16x32_bf16(al, wh, acc, 0, 0, 0);
        acc = __builtin_amdgcn_mfma_f32_16x16x32_bf16(ah, wl, acc, 0, 0, 0);
    }

    #pragma unroll
    for (int r = 0; r < 4; ++r) red[r * 256 + wave * 64 + lane] = acc[r];
    __syncthreads();

    const int o = n0 + l15;
    if (o < IFACE_) {
        const int m = m0 + quad * 4 + wave;
        const float* rg = red + wave * 256;
        float v = rg[lane] + rg[64 + lane] + rg[128 + lane] + rg[192 + lane] + bif[o];
        float rr;
        if (o < 80)        rr = tanhf_(v);
        else if (o < 84)   rr = softplusf_(v);
        else if (o < 104)  rr = tanhf_(v);
        else if (o < 105)  rr = softplusf_(v);
        else if (o < 125)  rr = sigmoidf_(v);
        else if (o < 145)  rr = tanhf_(v);
        else if (o < 151)  rr = sigmoidf_(v);
        else               rr = v;
        Sout[(size_t)m * IFP_ + o] = rr;
    }
}

// ---------------------------------------------------------------------------
// DNC memory step, WAVE-SYNCHRONOUS: one wave per batch element.
// Per-wave LDS scratch region W[1024] layout:
//   [0,163)   sif          [164,176) modes      [208,224) wwnew
//   [224,240) precold      [240,304) rwold      [304,368) rwnew
//   [368,624) lnk          [624,944) memS
// ---------------------------------------------------------------------------
__device__ void mem_batch(int b, int wl, float* W, const float* Sbuf,
    float* mem, float* link, float* prec, float* rw,
    float* ww, float* usage, __bf16* rvh, __bf16* rvl, int rvst)
{
    for (int i = wl; i < IFACE_; i += 64) W[i] = Sbuf[(size_t)b * IFP_ + i];
    if (wl < M_) W[224 + wl] = prec[(size_t)b * M_ + wl];
    W[240 + wl] = rw[(size_t)b * R_ * M_ + wl];
    #pragma unroll
    for (int k = 0; k < 4; ++k)
        W[368 + wl + 64 * k] = link[(size_t)b * M_ * M_ + wl + 64 * k];
    #pragma unroll
    for (int k = 0; k < 5; ++k)
        W[624 + wl + 64 * k] = mem[(size_t)b * M_ * WC_ + wl + 64 * k];
    WBAR_();

    if (wl < R_) {
        float a0 = W[151 + wl * 3], a1 = W[152 + wl * 3], a2 = W[153 + wl * 3];
        float mx = fmaxf(a0, fmaxf(a1, a2));
        float e0 = __expf(a0 - mx), e1 = __expf(a1 - mx), e2 = __expf(a2 - mx);
        float s = e0 + e1 + e2;
        W[164 + wl * 3] = e0 / s; W[165 + wl * 3] = e1 / s; W[166 + wl * 3] = e2 / s;
    }
    WBAR_();

    if (wl < M_) {
        const int m = wl;
        float wwold = ww[(size_t)b * M_ + m];
        float u = usage[(size_t)b * M_ + m];
        u = u + (1.f - u) * wwold;
        float psi = 1.f;
        #pragma unroll
        for (int r = 0; r < R_; ++r) psi *= (1.f - W[145 + r] * W[240 + r * 16 + m]);
        u *= psi;

        float kn2 = 0.f, mn2 = 0.f, dot = 0.f;
        #pragma unroll
        for (int w = 0; w < WC_; ++w) {
            float kv = W[84 + w], mv = W[624 + m * WC_ + w];
            kn2 += kv * kv; mn2 += mv * mv; dot += kv * mv;
        }
        float c = dot / ((sqrtf(kn2) + EPS_) * (sqrtf(mn2) + EPS_)) * W[104];
        float mx = c;
        #pragma unroll
        for (int off = 8; off; off >>= 1) mx = fmaxf(mx, __shfl_xor(mx, off, 16));
        float e = __expf(c - mx);
        float se = e;
        #pragma unroll
        for (int off = 8; off; off >>= 1) se += __shfl_xor(se, off, 16);
        float wcw = e / se;

        float uu = DELTA_ + (1.f - DELTA_) * u;
        int rank = 0;
        #pragma unroll
        for (int j = 0; j < 16; ++j) {
            float uj = __shfl(uu, j, 16);
            if (uj < uu || (uj == uu && j < m)) ++rank;
        }
        float prod = 1.f;
        #pragma unroll
        for (int j = 0; j < 16; ++j) {
            float uj = __shfl(uu, j, 16);
            int   rj = __shfl(rank, j, 16);
            if (rj < rank) prod *= uj;
        }
        float alloc = (1.f - uu) * prod;

        float ag = W[149], wg = W[150];
        float wwn = wg * (ag * alloc + (1.f - ag) * wcw);
        float sw = wwn;
        #pragma unroll
        for (int off = 8; off; off >>= 1) sw += __shfl_xor(sw, off, 16);

        W[208 + m] = wwn;
        usage[(size_t)b * M_ + m] = u;
        ww[(size_t)b * M_ + m]    = wwn;
        prec[(size_t)b * M_ + m]  = (1.f - sw) * W[224 + m] + wwn;
    }
    WBAR_();

    #pragma unroll
    for (int k = 0; k < 5; ++k) {
        int i = wl + 64 * k;
        int m = i / WC_, w = i - m * WC_;
        float nm = W[624 + i] * (1.f - W[208 + m] * W[105 + w]) + W[208 + m] * W[125 + w];
        W[624 + i] = nm;
        mem[(size_t)b * M_ * WC_ + i] = nm;
    }
    #pragma unroll
    for (int k = 0; k < 4; ++k) {
        int i = wl + 64 * k;
        int ii = i >> 4, jj = i & 15;
        float v = (1.f - W[208 + ii] - W[208 + jj]) * W[368 + i] + W[208 + ii] * W[224 + jj];
        if (ii == jj) v = 0.f;
        W[368 + i] = v;
        link[(size_t)b * M_ * M_ + i] = v;
    }
    WBAR_();

    {
        const int r = wl >> 4, m = wl & 15;
        float kn2 = 0.f, mn2 = 0.f, dot = 0.f;
        #pragma unroll
        for (int w = 0; w < WC_; ++w) {
            float kv = W[r * WC_ + w], mv = W[624 + m * WC_ + w];
            kn2 += kv * kv; mn2 += mv * mv; dot += kv * mv;
        }
        float c = dot / ((sqrtf(kn2) + EPS_) * (sqrtf(mn2) + EPS_)) * W[80 + r];
        float mx = c;
        #pragma unroll
        for (int off = 8; off; off >>= 1) mx = fmaxf(mx, __shfl_xor(mx, off, 16));
        float e = __expf(c - mx);
        float se = e;
        #pragma unroll
        for (int off = 8; off; off >>= 1) se += __shfl_xor(se, off, 16);
        float rc = e / se;

        float fwd = 0.f, bwd = 0.f;
        #pragma unroll
        for (int j = 0; j < M_; ++j) fwd += W[368 + m * 16 + j] * W[240 + r * 16 + j];
        #pragma unroll
        for (int i2 = 0; i2 < M_; ++i2) bwd += W[240 + r * 16 + i2] * W[368 + i2 * 16 + m];
        float v = W[164 + r * 3 + 0] * bwd + W[164 + r * 3 + 1] * fwd + W[164 + r * 3 + 2] * rc;
        W[304 + wl] = v;
        rw[(size_t)b * R_ * M_ + wl] = v;
    }
    WBAR_();

    #pragma unroll
    for (int k = 0; k < 2; ++k) {
        int i = wl + 64 * k;
        if (i < RW_) {
            int r = i / WC_, w = i - r * WC_;
            float s = 0.f;
            #pragma unroll
            for (int m = 0; m < M_; ++m) s += W[304 + r * 16 + m] * W[624 + m * WC_ + w];
            split2(s, &rvh[(size_t)b * rvst + IN_ + i], &rvl[(size_t)b * rvst + IN_ + i]);
        }
    }
}

// 4 batches per block, one wave each.
__device__ void mem_group4(int bbase, int tid, float* smem, const float* Sbuf,
    float* mem, float* link, float* prec, float* rw, float* ww, float* usage,
    __bf16* rvh, __bf16* rvl, int rvst)
{
    const int wave = tid >> 6, wl = tid & 63;
    mem_batch(bbase + wave, wl, smem + wave * 1024, Sbuf,
              mem, link, prec, rw, ww, usage, rvh, rvl, rvst);
}

// ---------------------------------------------------------------------------
// One pipeline slot, XCD-UNIFORM weight pinning (1040 blocks).
// Default dispatch maps block i -> XCD i%8, so decode (xcd = blk&7,
// k = blk>>3). Every stage runs on ALL 8 XCDs (130 blocks each — perfectly
// balanced, unlike R7's confinement), but the per-XCD sub-index picks the
// SAME jt/nt weight slice every slot:
//   k[0,4):    M0(t=s-3)  batch group i = xcd*4+k      (M state L2-pinned)
//   k[4,8):    M1(t=s-7)  batch group i = xcd*4+(k-4)
//   k[8,24):   A0(t=s)    jt = xcd*4+(j&3), mtp = (j>>2)*2   (573 KB W/XCD)
//   k[24,40):  B0(t=s-1)  same decode                        (524 KB)
//   k[40,56):  A1(t=s-4)
//   k[56,72):  B1(t=s-5)
//   k[72,104): Y(t=s-8)   nt = xcd*4+(j&3), mt = j>>2        (78 KB)
//   k[104,115):IF0(t=s-2) jt = j, mt = xcd                   (360 KB)
//   k[115,126):IF1(t=s-6) jt = j, mt = xcd
//   k[126,130):x(s+1)     chunk = xcd*4+(k-126)
// Per-XCD pinned weight set ~3.4 MB < 4.19 MB L2 -> weights stop streaming
// from HBM every slot. Mapping is perf-only; correctness from launch-boundary
// coherence as before. Math bit-identical to R8.
// ---------------------------------------------------------------------------
__global__ __launch_bounds__(256, 6) void slot_kernel(P p, int s)
{
    __shared__ float smem[4096];
    const int blk = blockIdx.x, tid = threadIdx.x;
    const int xcd = blk & 7, k = blk >> 3;

    if (k < 4) {                           // M0(t=s-3)
        int t = s - 3;
        if (t >= 0 && t < T_) {
            int i = xcd * 4 + k;
            mem_group4(i * 4, tid, smem, p.S0[t & 1],
                p.mem0, p.link0, p.prec0, p.rw0, p.ww0, p.us0,
                p.a11h[t & 3], p.a11l[t & 3], K1P_);
        }
    } else if (k < 8) {                    // M1(t=s-7)
        int t = s - 7;
        if (t >= 0 && t < T_) {
            int i = xcd * 4 + (k - 4);
            mem_group4(i * 4, tid, smem, p.S1[t & 1],
                p.mem1, p.link1, p.prec1, p.rw1, p.ww1, p.us1,
                p.yh[t & 3], p.yl[t & 3], KOP_);
        }
    } else if (k < 24) {                   // A0(t=s)
        int t = s;
        if (t < T_) {
            int j = k - 8;
            gemm_lstm_tile2(tid, xcd * 4 + (j & 3), (j >> 2) * 2, smem,
                p.a10h[t & 3], p.a10l[t & 3], K1P_, p.w10, K1P_ / 32,
                p.bih0, p.bhh0, p.c00,
                p.a10h[(t + 1) & 3], p.a10l[(t + 1) & 3], K1P_, NNIN_,
                p.a20h[t & 3], p.a20l[t & 3], K2P_, 0, 0);
        }
    } else if (k < 40) {                   // B0(t=s-1)
        int t = s - 1;
        if (t >= 0 && t < T_) {
            int j = k - 24;
            gemm_lstm_tile2(tid, xcd * 4 + (j & 3), (j >> 2) * 2, smem,
                p.a20h[t & 3], p.a20l[t & 3], K2P_, p.w20, K2P_ / 32,
                p.bih1, p.bhh1, p.c01,
                p.a20h[(t + 1) & 3], p.a20l[(t + 1) & 3], K2P_, H_,
                p.a11h[t & 3], p.a11l[t & 3], K1P_, 0, 1);
        }
    } else if (k < 56) {                   // A1(t=s-4)
        int t = s - 4;
        if (t >= 0 && t < T_) {
            int j = k - 40;
            gemm_lstm_tile2(tid, xcd * 4 + (j & 3), (j >> 2) * 2, smem,
                p.a11h[t & 3], p.a11l[t & 3], K1P_, p.w11, K1P_ / 32,
                p.bih0 + 2048, p.bhh0 + 2048, p.c10,
                p.a11h[(t + 1) & 3], p.a11l[(t + 1) & 3], K1P_, NNIN_,
                p.a21h[t & 3], p.a21l[t & 3], K2P_, 0, 0);
        }
    } else if (k < 72) {                   // B1(t=s-5)
        int t = s - 5;
        if (t >= 0 && t < T_) {
            int j = k - 56;
            gemm_lstm_tile2(tid, xcd * 4 + (j & 3), (j >> 2) * 2, smem,
                p.a21h[t & 3], p.a21l[t & 3], K2P_, p.w21, K2P_ / 32,
                p.bih1 + 2048, p.bhh1 + 2048, p.c11,
                p.a21h[(t + 1) & 3], p.a21l[(t + 1) & 3], K2P_, H_,
                p.yh[t & 3], p.yl[t & 3], KOP_, 0, 1);
        }
    } else if (k < 104) {                  // Y(t=s-8)
        int t = s - 8;
        if (t >= 0 && t < T_) {
            int j = k - 72;
            gemm_plain_tile(tid, xcd * 4 + (j & 3), j >> 2, smem,
                p.yh[t & 3], p.yl[t & 3], KOP_, p.wo, KOP_, KOP_ / 32,
                p.bout, p.out + (size_t)t * IN_, T_ * IN_);
        }
    } else if (k < 115) {                  // IF0(t=s-2)
        int t = s - 2;
        if (t >= 0 && t < T_) {
            int j = k - 104;
            gemm_iface_tile(tid, j, xcd, smem,
                p.a11h[t & 3], p.a11l[t & 3], K1P_,
                p.wif0h, p.wif0l, p.bif0, p.S0[t & 1]);
        }
    } else if (k < 126) {                  // IF1(t=s-6)
        int t = s - 6;
        if (t >= 0 && t < T_) {
            int j = k - 115;
            gemm_iface_tile(tid, j, xcd, smem,
                p.yh[t & 3], p.yl[t & 3], KOP_,
                p.wif1h, p.wif1l, p.bif1, p.S1[t & 1]);
        }
    } else {                               // x(s+1) convert
        int tn = s + 1;
        if (tn < T_) {
            int c = xcd * 4 + (k - 126);
            for (int i = c * 256 + tid; i < B_ * IN_; i += 32 * 256) {
                int b = i >> 9, j = i & 511;
                float v = p.x[((size_t)b * T_ + tn) * IN_ + j];
                split2(v, &p.a10h[tn & 3][(size_t)b * K1P_ + j],
                          &p.a10l[tn & 3][(size_t)b * K1P_ + j]);
            }
        }
    }
}

// ---------------------------------------------------------------------------
// Setup kernels
// ---------------------------------------------------------------------------
struct ConvArgs { const float* s1; const float* s2; __bf16* dst; int K1, K2, Kd; };
struct ConvArgs4 { ConvArgs a[4]; };

__global__ __launch_bounds__(256) void conv_lstm(ConvArgs4 ca)
{
    ConvArgs c = ca.a[blockIdx.z];
    int k = blockIdx.x * 256 + threadIdx.x;
    if (k >= c.Kd) return;
    int n = blockIdx.y;
    float v = 0.f;
    if (k < c.K1) v = c.s1[(size_t)n * c.K1 + k];
    else if (k < c.K1 + c.K2) v = c.s2[(size_t)n * c.K2 + (k - c.K1)];
    c.dst[(size_t)n * c.Kd + k] = (__bf16)v;
}

__global__ __launch_bounds__(256) void conv_hi(
    const float* __restrict__ s1, int K1, const float* __restrict__ s2, int K2,
    int Nsrc, __bf16* __restrict__ hi, int Kd)
{
    int k = blockIdx.x * 256 + threadIdx.x;
    int n = blockIdx.y;
    if (k >= Kd) return;
    float v = 0.f;
    if (n < Nsrc) {
        if (k < K1) v = s1[(size_t)n * K1 + k];
        else if (k < K1 + K2) v = s2[(size_t)n * K2 + (k - K1)];
    }
    hi[(size_t)n * Kd + k] = (__bf16)v;
}

__global__ __launch_bounds__(256) void conv_hl(
    const float* __restrict__ src, int Nsrc, int K,
    __bf16* __restrict__ hi, __bf16* __restrict__ lo)
{
    int k = blockIdx.x * 256 + threadIdx.x;
    int n = blockIdx.y;
    if (k >= K) return;
    float v = (n < Nsrc) ? src[(size_t)n * K + k] : 0.f;
    split2(v, &hi[(size_t)n * K + k], &lo[(size_t)n * K + k]);
}

__global__ __launch_bounds__(256) void build_inp(const float* __restrict__ x,
                                                 __bf16* __restrict__ a1h,
                                                 __bf16* __restrict__ a1l)
{
    int idx = blockIdx.x * 256 + threadIdx.x;
    if (idx >= B_ * IN_) return;
    int b = idx >> 9, j = idx & 511;
    float v = x[(size_t)b * T_ * IN_ + j];
    split2(v, &a1h[b * K1P_ + j], &a1l[b * K1P_ + j]);
}

// ---------------------------------------------------------------------------
extern "C" void kernel_launch(void* const* d_in, const int* in_sizes, int n_in,
                              void* d_out, int out_size, void* d_ws, size_t ws_size,
                              hipStream_t stream)
{
    const float* x       = (const float*)d_in[0];
    const float* W_ih0   = (const float*)d_in[1];
    const float* W_hh0   = (const float*)d_in[2];
    const float* b_ih0   = (const float*)d_in[3];
    const float* b_hh0   = (const float*)d_in[4];
    const float* W_ih1   = (const float*)d_in[5];
    const float* W_hh1   = (const float*)d_in[6];
    const float* b_ih1   = (const float*)d_in[7];
    const float* b_hh1   = (const float*)d_in[8];
    const float* W_iface = (const float*)d_in[9];
    const float* b_iface = (const float*)d_in[10];
    const float* W_out   = (const float*)d_in[11];
    const float* b_out   = (const float*)d_in[12];

    P p;
    p.x = x;
    p.bih0 = b_ih0; p.bhh0 = b_hh0; p.bih1 = b_ih1; p.bhh1 = b_hh1;
    p.bif0 = b_iface; p.bif1 = b_iface + IFACE_;
    p.bout = b_out;
    p.out = (float*)d_out;

    char* ptr = (char*)d_ws;
    auto alloc = [&](size_t bytes) { char* r = ptr; ptr += (bytes + 255) & ~(size_t)255; return r; };

    // ---- zero zone (memset each call) ----
    char* zstart = ptr;
    for (int q = 0; q < 4; ++q) { p.a10h[q] = (__bf16*)alloc(B_ * K1P_ * 2); p.a10l[q] = (__bf16*)alloc(B_ * K1P_ * 2); }
    for (int q = 0; q < 4; ++q) { p.a11h[q] = (__bf16*)alloc(B_ * K1P_ * 2); p.a11l[q] = (__bf16*)alloc(B_ * K1P_ * 2); }
    for (int q = 0; q < 4; ++q) { p.a20h[q] = (__bf16*)alloc(B_ * K2P_ * 2); p.a20l[q] = (__bf16*)alloc(B_ * K2P_ * 2); }
    for (int q = 0; q < 4; ++q) { p.a21h[q] = (__bf16*)alloc(B_ * K2P_ * 2); p.a21l[q] = (__bf16*)alloc(B_ * K2P_ * 2); }
    for (int q = 0; q < 4; ++q) { p.yh[q]  = (__bf16*)alloc(B_ * KOP_ * 2);  p.yl[q]  = (__bf16*)alloc(B_ * KOP_ * 2); }
    p.c00 = (float*)alloc((size_t)B_ * H_ * 4);
    p.c01 = (float*)alloc((size_t)B_ * H_ * 4);
    p.c10 = (float*)alloc((size_t)B_ * H_ * 4);
    p.c11 = (float*)alloc((size_t)B_ * H_ * 4);
    p.mem0  = (float*)alloc((size_t)B_ * M_ * WC_ * 4);
    p.link0 = (float*)alloc((size_t)B_ * M_ * M_ * 4);
    p.prec0 = (float*)alloc((size_t)B_ * M_ * 4);
    p.rw0   = (float*)alloc((size_t)B_ * R_ * M_ * 4);
    p.ww0   = (float*)alloc((size_t)B_ * M_ * 4);
    p.us0   = (float*)alloc((size_t)B_ * M_ * 4);
    p.mem1  = (float*)alloc((size_t)B_ * M_ * WC_ * 4);
    p.link1 = (float*)alloc((size_t)B_ * M_ * M_ * 4);
    p.prec1 = (float*)alloc((size_t)B_ * M_ * 4);
    p.rw1   = (float*)alloc((size_t)B_ * R_ * M_ * 4);
    p.ww1   = (float*)alloc((size_t)B_ * M_ * 4);
    p.us1   = (float*)alloc((size_t)B_ * M_ * 4);
    size_t zbytes = (size_t)(ptr - zstart);

    // ---- weights (rewritten every call) ----
    p.w10 = (__bf16*)alloc(2048ull * K1P_ * 2);
    p.w11 = (__bf16*)alloc(2048ull * K1P_ * 2);
    p.w20 = (__bf16*)alloc(2048ull * K2P_ * 2);
    p.w21 = (__bf16*)alloc(2048ull * K2P_ * 2);
    p.wo  = (__bf16*)alloc(512ull * KOP_ * 2);
    p.wif0h = (__bf16*)alloc((size_t)IFP_ * 512 * 2);
    p.wif0l = (__bf16*)alloc((size_t)IFP_ * 512 * 2);
    p.wif1h = (__bf16*)alloc((size_t)IFP_ * 512 * 2);
    p.wif1l = (__bf16*)alloc((size_t)IFP_ * 512 * 2);
    for (int q = 0; q < 2; ++q) p.S0[q] = (float*)alloc((size_t)B_ * IFP_ * 4);
    for (int q = 0; q < 2; ++q) p.S1[q] = (float*)alloc((size_t)B_ * IFP_ * 4);

    hipMemsetAsync(zstart, 0, zbytes, stream);

    ConvArgs4 ca;
    ca.a[0] = { W_ih0,                 W_hh0,                 p.w10, NNIN_, H_, K1P_ };
    ca.a[1] = { W_ih0 + 2048ull*NNIN_, W_hh0 + 2048ull*H_,    p.w11, NNIN_, H_, K1P_ };
    ca.a[2] = { W_ih1,                 W_hh1,                 p.w20, H_,    H_, K2P_ };
    ca.a[3] = { W_ih1 + 2048ull*H_,    W_hh1 + 2048ull*H_,    p.w21, H_,    H_, K2P_ };
    conv_lstm<<<dim3((K1P_ + 255) / 256, 2048, 4), 256, 0, stream>>>(ca);

    conv_hi<<<dim3((KOP_ + 255) / 256, 512), 256, 0, stream>>>(
        W_out, NNIN_, nullptr, 0, 512, p.wo, KOP_);
    conv_hl<<<dim3(2, IFP_), 256, 0, stream>>>(
        W_iface, IFACE_, 512, p.wif0h, p.wif0l);
    conv_hl<<<dim3(2, IFP_), 256, 0, stream>>>(
        W_iface + (size_t)IFACE_ * 512, IFACE_, 512, p.wif1h, p.wif1l);
    build_inp<<<(B_ * IN_ + 255) / 256, 256, 0, stream>>>(x, p.a10h[0], p.a10l[0]);

    // 40 pipeline slots cover t=0..31 for all 9 stages
    for (int s = 0; s < T_ + 8; ++s) {
        slot_kernel<<<1040, 256, 0, stream>>>(p, s);
    }
}

// Round 10
// 692.914 us; speedup vs baseline: 2.0448x; 1.3031x over previous
//
#include <hip/hip_runtime.h>
#include <hip/hip_bf16.h>
#include <math.h>

#define B_ 128
#define T_ 32
#define IN_ 512
#define H_ 512
#define M_ 16
#define WC_ 20
#define R_ 4
#define RW_ 80
#define NNIN_ 592
#define IFACE_ 163
#define IFP_ 176
#define K1P_ 1120
#define K2P_ 1024
#define KOP_ 608
#define CLIP_ 20.0f
#define EPS_ 1e-6f
#define DELTA_ 5e-6f

typedef __bf16 bf16x8 __attribute__((ext_vector_type(8)));
typedef float f32x4 __attribute__((ext_vector_type(4)));

__device__ __forceinline__ float sigmoidf_(float x) { return 1.0f / (1.0f + __expf(-x)); }
__device__ __forceinline__ float tanhf_(float x) {
    float e = __expf(-2.f * fabsf(x));
    float t = (1.f - e) / (1.f + e);
    return copysignf(t, x);
}
__device__ __forceinline__ float softplusf_(float x) {
    return fmaxf(x, 0.0f) + log1pf(__expf(-fabsf(x)));
}
__device__ __forceinline__ void split2(float v, __bf16* hp, __bf16* lp) {
    __bf16 h = (__bf16)v;
    *hp = h;
    *lp = (__bf16)(v - (float)h);
}
#define WBAR_() __builtin_amdgcn_wave_barrier()

// ---------------------------------------------------------------------------
// Parameter block. ALL activations single-limb bf16 (error budget: measured
// absmax 2^-9 vs threshold 2^-7; LSTM weights are already single-limb so
// activation quantization adds a same-order term). iface weights stay 2-limb.
// a10 repacked to [x | h00] stride K2P_=1024 — layer-0's last_read input is
// identically zero in the reference, so its 80 columns (and w10's matching
// dead columns) are deleted.
// ---------------------------------------------------------------------------
struct P {
    const float *x, *bih0, *bhh0, *bih1, *bhh1, *bif0, *bif1, *bout;
    float* out;
    __bf16 *a10[4];   // [x | h00], stride K2P_
    __bf16 *a11[4];   // [out0 | rv0 | h10], stride K1P_
    __bf16 *a20[4];   // [h0A | h01], stride K2P_
    __bf16 *a21[4];   // [h1A | h11], stride K2P_
    __bf16 *y[4];     // [out1 | rv1 | pad], stride KOP_
    float *c00, *c01, *c10, *c11;
    float *mem0, *link0, *prec0, *rw0, *ww0, *us0;
    float *mem1, *link1, *prec1, *rw1, *ww1, *us1;
    __bf16 *w10, *w20, *w11, *w21, *wo;
    __bf16 *wif0h, *wif0l, *wif1h, *wif1l;   // [IFP_ x 512]
    float *S0[2], *S1[2];                    // [B_ x IFP_] activated iface
};

// ---------------------------------------------------------------------------
// mt-PAIRED fused LSTM GEMM tile, single-limb: 32 batch rows x 16 hidden
// cols of all 4 gates. Per K-step: 2 A loads + 4 W loads + 8 MFMAs (was
// 4+4+16 with 2-limb A). 4 waves split K; all-wave LDS reduce + parallel
// epilogue, run twice. red = 16*256 floats (16 KB).
// ---------------------------------------------------------------------------
__device__ __forceinline__ void gemm_lstm_tile2(
    int tid, int jt, int mt0, float* red,
    const __bf16* A, int KS,
    const __bf16* W, int nsteps,
    const float* b1, const float* b2, float* cst,
    __bf16* d1, int st1, int off1,
    __bf16* d2, int st2, int off2, int clip2)
{
    const int wave = tid >> 6, lane = tid & 63;
    const int l15 = lane & 15, quad = lane >> 4;
    const int j0 = jt * 16, m0 = mt0 * 16;

    f32x4 acc0[4], acc1[4];
    #pragma unroll
    for (int g = 0; g < 4; ++g)
        #pragma unroll
        for (int i = 0; i < 4; ++i) { acc0[g][i] = 0.f; acc1[g][i] = 0.f; }

    const int ks = (wave * nsteps) >> 2;
    const int ke = ((wave + 1) * nsteps) >> 2;

    size_t aoff0 = (size_t)(m0 + l15) * KS + ks * 32 + quad * 8;
    size_t aoff1 = aoff0 + (size_t)16 * KS;
    size_t woff[4];
    #pragma unroll
    for (int g = 0; g < 4; ++g)
        woff[g] = (size_t)(g * 512 + j0 + l15) * KS + ks * 32 + quad * 8;

    for (int s = ks; s < ke; ++s) {
        bf16x8 ah0 = *(const bf16x8*)(A + aoff0);
        bf16x8 ah1 = *(const bf16x8*)(A + aoff1);
        aoff0 += 32; aoff1 += 32;
        #pragma unroll
        for (int g = 0; g < 4; ++g) {
            bf16x8 wh = *(const bf16x8*)(W + woff[g]);
            woff[g] += 32;
            acc0[g] = __builtin_amdgcn_mfma_f32_16x16x32_bf16(ah0, wh, acc0[g], 0, 0, 0);
            acc1[g] = __builtin_amdgcn_mfma_f32_16x16x32_bf16(ah1, wh, acc1[g], 0, 0, 0);
        }
    }

    const int col = j0 + l15;
    float bg[4];
    #pragma unroll
    for (int g = 0; g < 4; ++g) bg[g] = b1[g * 512 + col] + b2[g * 512 + col];

    #pragma unroll
    for (int pair = 0; pair < 2; ++pair) {
        #pragma unroll
        for (int g = 0; g < 4; ++g)
            #pragma unroll
            for (int r = 0; r < 4; ++r)
                red[(g * 4 + r) * 256 + wave * 64 + lane] =
                    pair ? acc1[g][r] : acc0[g][r];
        __syncthreads();

        const int m = m0 + pair * 16 + quad * 4 + wave;
        float gv[4];
        #pragma unroll
        for (int g = 0; g < 4; ++g) {
            const float* rg = red + (g * 4 + wave) * 256;
            gv[g] = rg[lane] + rg[64 + lane] + rg[128 + lane] + rg[192 + lane] + bg[g];
        }
        float cold = cst[m * H_ + col];
        float cn = sigmoidf_(gv[1]) * cold + sigmoidf_(gv[0]) * tanhf_(gv[2]);
        cst[m * H_ + col] = cn;
        float h = sigmoidf_(gv[3]) * tanhf_(cn);
        d1[(size_t)m * st1 + off1 + col] = (__bf16)h;
        float h2 = clip2 ? fminf(fmaxf(h, -CLIP_), CLIP_) : h;
        d2[(size_t)m * st2 + off2 + col] = (__bf16)h2;
        if (pair == 0) __syncthreads();
    }
}

// ---------------------------------------------------------------------------
// Plain GEMM tile (out projection), single-limb A, all-wave epilogue.
// ---------------------------------------------------------------------------
__device__ __forceinline__ void gemm_plain_tile(
    int tid, int nt, int mt, float* red,
    const __bf16* A, int AS,
    const __bf16* W, int WS,
    int nsteps, const float* bias, float* C, int ldc)
{
    const int wave = tid >> 6, lane = tid & 63;
    const int l15 = lane & 15, quad = lane >> 4;
    const int n0 = nt * 16, m0 = mt * 16;

    f32x4 acc;
    #pragma unroll
    for (int i = 0; i < 4; ++i) acc[i] = 0.f;

    const int ks = (wave * nsteps) >> 2;
    const int ke = ((wave + 1) * nsteps) >> 2;

    size_t aoff = (size_t)(m0 + l15) * AS + ks * 32 + quad * 8;
    size_t woff = (size_t)(n0 + l15) * WS + ks * 32 + quad * 8;

    for (int s = ks; s < ke; ++s) {
        bf16x8 ah = *(const bf16x8*)(A + aoff);
        bf16x8 wh = *(const bf16x8*)(W + woff);
        aoff += 32; woff += 32;
        acc = __builtin_amdgcn_mfma_f32_16x16x32_bf16(ah, wh, acc, 0, 0, 0);
    }

    #pragma unroll
    for (int r = 0; r < 4; ++r) red[r * 256 + wave * 64 + lane] = acc[r];
    __syncthreads();

    const int col = n0 + l15;
    const int m = m0 + quad * 4 + wave;
    const float* rg = red + wave * 256;
    float v = rg[lane] + rg[64 + lane] + rg[128 + lane] + rg[192 + lane] + bias[col];
    C[(size_t)m * ldc + col] = v;
}

// ---------------------------------------------------------------------------
// iface GEMM tile: S = act(out @ Wif^T + bif). A single-limb x W 2-limb,
// 2 MFMAs per K-step (ah*wh + ah*wl). K = 512 fixed -> 16 steps, 4 per wave.
// ---------------------------------------------------------------------------
__device__ __forceinline__ void gemm_iface_tile(
    int tid, int jt, int mt, float* red,
    const __bf16* A, int AS,
    const __bf16* Wh, const __bf16* Wl,
    const float* bif, float* Sout)
{
    const int wave = tid >> 6, lane = tid & 63;
    const int l15 = lane & 15, quad = lane >> 4;
    const int n0 = jt * 16, m0 = mt * 16;

    f32x4 acc;
    #pragma unroll
    for (int i = 0; i < 4; ++i) acc[i] = 0.f;

    size_t aoff = (size_t)(m0 + l15) * AS + wave * 128 + quad * 8;
    size_t woff = (size_t)(n0 + l15) * 512 + wave * 128 + quad * 8;

    #pragma unroll
    for (int s = 0; s < 4; ++s) {
        bf16x8 ah = *(const bf16x8*)(A + aoff);
        bf16x8 wh = *(const bf16x8*)(Wh + woff);
        bf16x8 wl = *(const bf16x8*)(Wl + woff);
        aoff += 32; woff += 32;
        acc = __builtin_amdgcn_mfma_f32_16x16x32_bf16(ah, wh, acc, 0, 0, 0);
        acc = __builtin_amdgcn_mfma_f32_16x16x32_bf16(ah, wl, acc, 0, 0, 0);
    }

    #pragma unroll
    for (int r = 0; r < 4; ++r) red[r * 256 + wave * 64 + lane] = acc[r];
    __syncthreads();

    const int o = n0 + l15;
    if (o < IFACE_) {
        const int m = m0 + quad * 4 + wave;
        const float* rg = red + wave * 256;
        float v = rg[lane] + rg[64 + lane] + rg[128 + lane] + rg[192 + lane] + bif[o];
        float rr;
        if (o < 80)        rr = tanhf_(v);
        else if (o < 84)   rr = softplusf_(v);
        else if (o < 104)  rr = tanhf_(v);
        else if (o < 105)  rr = softplusf_(v);
        else if (o < 125)  rr = sigmoidf_(v);
        else if (o < 145)  rr = tanhf_(v);
        else if (o < 151)  rr = sigmoidf_(v);
        else               rr = v;
        Sout[(size_t)m * IFP_ + o] = rr;
    }
}

// ---------------------------------------------------------------------------
// DNC memory step, WAVE-SYNCHRONOUS: one wave per batch element.
// Per-wave LDS scratch region W[1024] layout:
//   [0,163)   sif          [164,176) modes      [208,224) wwnew
//   [224,240) precold      [240,304) rwold      [304,368) rwnew
//   [368,624) lnk          [624,944) memS
// ---------------------------------------------------------------------------
__device__ void mem_batch(int b, int wl, float* W, const float* Sbuf,
    float* mem, float* link, float* prec, float* rw,
    float* ww, float* usage, __bf16* rv, int rvst)
{
    for (int i = wl; i < IFACE_; i += 64) W[i] = Sbuf[(size_t)b * IFP_ + i];
    if (wl < M_) W[224 + wl] = prec[(size_t)b * M_ + wl];
    W[240 + wl] = rw[(size_t)b * R_ * M_ + wl];
    #pragma unroll
    for (int k = 0; k < 4; ++k)
        W[368 + wl + 64 * k] = link[(size_t)b * M_ * M_ + wl + 64 * k];
    #pragma unroll
    for (int k = 0; k < 5; ++k)
        W[624 + wl + 64 * k] = mem[(size_t)b * M_ * WC_ + wl + 64 * k];
    WBAR_();

    if (wl < R_) {
        float a0 = W[151 + wl * 3], a1 = W[152 + wl * 3], a2 = W[153 + wl * 3];
        float mx = fmaxf(a0, fmaxf(a1, a2));
        float e0 = __expf(a0 - mx), e1 = __expf(a1 - mx), e2 = __expf(a2 - mx);
        float s = e0 + e1 + e2;
        W[164 + wl * 3] = e0 / s; W[165 + wl * 3] = e1 / s; W[166 + wl * 3] = e2 / s;
    }
    WBAR_();

    if (wl < M_) {
        const int m = wl;
        float wwold = ww[(size_t)b * M_ + m];
        float u = usage[(size_t)b * M_ + m];
        u = u + (1.f - u) * wwold;
        float psi = 1.f;
        #pragma unroll
        for (int r = 0; r < R_; ++r) psi *= (1.f - W[145 + r] * W[240 + r * 16 + m]);
        u *= psi;

        float kn2 = 0.f, mn2 = 0.f, dot = 0.f;
        #pragma unroll
        for (int w = 0; w < WC_; ++w) {
            float kv = W[84 + w], mv = W[624 + m * WC_ + w];
            kn2 += kv * kv; mn2 += mv * mv; dot += kv * mv;
        }
        float c = dot / ((sqrtf(kn2) + EPS_) * (sqrtf(mn2) + EPS_)) * W[104];
        float mx = c;
        #pragma unroll
        for (int off = 8; off; off >>= 1) mx = fmaxf(mx, __shfl_xor(mx, off, 16));
        float e = __expf(c - mx);
        float se = e;
        #pragma unroll
        for (int off = 8; off; off >>= 1) se += __shfl_xor(se, off, 16);
        float wcw = e / se;

        float uu = DELTA_ + (1.f - DELTA_) * u;
        int rank = 0;
        #pragma unroll
        for (int j = 0; j < 16; ++j) {
            float uj = __shfl(uu, j, 16);
            if (uj < uu || (uj == uu && j < m)) ++rank;
        }
        float prod = 1.f;
        #pragma unroll
        for (int j = 0; j < 16; ++j) {
            float uj = __shfl(uu, j, 16);
            int   rj = __shfl(rank, j, 16);
            if (rj < rank) prod *= uj;
        }
        float alloc = (1.f - uu) * prod;

        float ag = W[149], wg = W[150];
        float wwn = wg * (ag * alloc + (1.f - ag) * wcw);
        float sw = wwn;
        #pragma unroll
        for (int off = 8; off; off >>= 1) sw += __shfl_xor(sw, off, 16);

        W[208 + m] = wwn;
        usage[(size_t)b * M_ + m] = u;
        ww[(size_t)b * M_ + m]    = wwn;
        prec[(size_t)b * M_ + m]  = (1.f - sw) * W[224 + m] + wwn;
    }
    WBAR_();

    #pragma unroll
    for (int k = 0; k < 5; ++k) {
        int i = wl + 64 * k;
        int m = i / WC_, w = i - m * WC_;
        float nm = W[624 + i] * (1.f - W[208 + m] * W[105 + w]) + W[208 + m] * W[125 + w];
        W[624 + i] = nm;
        mem[(size_t)b * M_ * WC_ + i] = nm;
    }
    #pragma unroll
    for (int k = 0; k < 4; ++k) {
        int i = wl + 64 * k;
        int ii = i >> 4, jj = i & 15;
        float v = (1.f - W[208 + ii] - W[208 + jj]) * W[368 + i] + W[208 + ii] * W[224 + jj];
        if (ii == jj) v = 0.f;
        W[368 + i] = v;
        link[(size_t)b * M_ * M_ + i] = v;
    }
    WBAR_();

    {
        const int r = wl >> 4, m = wl & 15;
        float kn2 = 0.f, mn2 = 0.f, dot = 0.f;
        #pragma unroll
        for (int w = 0; w < WC_; ++w) {
            float kv = W[r * WC_ + w], mv = W[624 + m * WC_ + w];
            kn2 += kv * kv; mn2 += mv * mv; dot += kv * mv;
        }
        float c = dot / ((sqrtf(kn2) + EPS_) * (sqrtf(mn2) + EPS_)) * W[80 + r];
        float mx = c;
        #pragma unroll
        for (int off = 8; off; off >>= 1) mx = fmaxf(mx, __shfl_xor(mx, off, 16));
        float e = __expf(c - mx);
        float se = e;
        #pragma unroll
        for (int off = 8; off; off >>= 1) se += __shfl_xor(se, off, 16);
        float rc = e / se;

        float fwd = 0.f, bwd = 0.f;
        #pragma unroll
        for (int j = 0; j < M_; ++j) fwd += W[368 + m * 16 + j] * W[240 + r * 16 + j];
        #pragma unroll
        for (int i2 = 0; i2 < M_; ++i2) bwd += W[240 + r * 16 + i2] * W[368 + i2 * 16 + m];
        float v = W[164 + r * 3 + 0] * bwd + W[164 + r * 3 + 1] * fwd + W[164 + r * 3 + 2] * rc;
        W[304 + wl] = v;
        rw[(size_t)b * R_ * M_ + wl] = v;
    }
    WBAR_();

    #pragma unroll
    for (int k = 0; k < 2; ++k) {
        int i = wl + 64 * k;
        if (i < RW_) {
            int r = i / WC_, w = i - r * WC_;
            float s = 0.f;
            #pragma unroll
            for (int m = 0; m < M_; ++m) s += W[304 + r * 16 + m] * W[624 + m * WC_ + w];
            rv[(size_t)b * rvst + IN_ + i] = (__bf16)s;
        }
    }
}

// 4 batches per block, one wave each.
__device__ void mem_group4(int bbase, int tid, float* smem, const float* Sbuf,
    float* mem, float* link, float* prec, float* rw, float* ww, float* usage,
    __bf16* rv, int rvst)
{
    const int wave = tid >> 6, wl = tid & 63;
    mem_batch(bbase + wave, wl, smem + wave * 1024, Sbuf,
              mem, link, prec, rw, ww, usage, rv, rvst);
}

// ---------------------------------------------------------------------------
// One pipeline slot, XCD-UNIFORM weight pinning (1040 blocks), identical
// stage decode to R9. Single-limb activations everywhere; a10 K = 1024.
//   k[0,4):    M0(t=s-3)   k[4,8):   M1(t=s-7)
//   k[8,24):   A0(t=s)     k[24,40): B0(t=s-1)
//   k[40,56):  A1(t=s-4)   k[56,72): B1(t=s-5)
//   k[72,104): Y(t=s-8)    k[104,115): IF0(t=s-2)
//   k[115,126):IF1(t=s-6)  k[126,130): x(s+1)
// ---------------------------------------------------------------------------
__global__ __launch_bounds__(256, 6) void slot_kernel(P p, int s)
{
    __shared__ float smem[4096];
    const int blk = blockIdx.x, tid = threadIdx.x;
    const int xcd = blk & 7, k = blk >> 3;

    if (k < 4) {                           // M0(t=s-3)
        int t = s - 3;
        if (t >= 0 && t < T_) {
            int i = xcd * 4 + k;
            mem_group4(i * 4, tid, smem, p.S0[t & 1],
                p.mem0, p.link0, p.prec0, p.rw0, p.ww0, p.us0,
                p.a11[t & 3], K1P_);
        }
    } else if (k < 8) {                    // M1(t=s-7)
        int t = s - 7;
        if (t >= 0 && t < T_) {
            int i = xcd * 4 + (k - 4);
            mem_group4(i * 4, tid, smem, p.S1[t & 1],
                p.mem1, p.link1, p.prec1, p.rw1, p.ww1, p.us1,
                p.y[t & 3], KOP_);
        }
    } else if (k < 24) {                   // A0(t=s)
        int t = s;
        if (t < T_) {
            int j = k - 8;
            gemm_lstm_tile2(tid, xcd * 4 + (j & 3), (j >> 2) * 2, smem,
                p.a10[t & 3], K2P_, p.w10, K2P_ / 32,
                p.bih0, p.bhh0, p.c00,
                p.a10[(t + 1) & 3], K2P_, 512,
                p.a20[t & 3], K2P_, 0, 0);
        }
    } else if (k < 40) {                   // B0(t=s-1)
        int t = s - 1;
        if (t >= 0 && t < T_) {
            int j = k - 24;
            gemm_lstm_tile2(tid, xcd * 4 + (j & 3), (j >> 2) * 2, smem,
                p.a20[t & 3], K2P_, p.w20, K2P_ / 32,
                p.bih1, p.bhh1, p.c01,
                p.a20[(t + 1) & 3], K2P_, H_,
                p.a11[t & 3], K1P_, 0, 1);
        }
    } else if (k < 56) {                   // A1(t=s-4)
        int t = s - 4;
        if (t >= 0 && t < T_) {
            int j = k - 40;
            gemm_lstm_tile2(tid, xcd * 4 + (j & 3), (j >> 2) * 2, smem,
                p.a11[t & 3], K1P_, p.w11, K1P_ / 32,
                p.bih0 + 2048, p.bhh0 + 2048, p.c10,
                p.a11[(t + 1) & 3], K1P_, NNIN_,
                p.a21[t & 3], K2P_, 0, 0);
        }
    } else if (k < 72) {                   // B1(t=s-5)
        int t = s - 5;
        if (t >= 0 && t < T_) {
            int j = k - 56;
            gemm_lstm_tile2(tid, xcd * 4 + (j & 3), (j >> 2) * 2, smem,
                p.a21[t & 3], K2P_, p.w21, K2P_ / 32,
                p.bih1 + 2048, p.bhh1 + 2048, p.c11,
                p.a21[(t + 1) & 3], K2P_, H_,
                p.y[t & 3], KOP_, 0, 1);
        }
    } else if (k < 104) {                  // Y(t=s-8)
        int t = s - 8;
        if (t >= 0 && t < T_) {
            int j = k - 72;
            gemm_plain_tile(tid, xcd * 4 + (j & 3), j >> 2, smem,
                p.y[t & 3], KOP_, p.wo, KOP_, KOP_ / 32,
                p.bout, p.out + (size_t)t * IN_, T_ * IN_);
        }
    } else if (k < 115) {                  // IF0(t=s-2)
        int t = s - 2;
        if (t >= 0 && t < T_) {
            int j = k - 104;
            gemm_iface_tile(tid, j, xcd, smem,
                p.a11[t & 3], K1P_,
                p.wif0h, p.wif0l, p.bif0, p.S0[t & 1]);
        }
    } else if (k < 126) {                  // IF1(t=s-6)
        int t = s - 6;
        if (t >= 0 && t < T_) {
            int j = k - 115;
            gemm_iface_tile(tid, j, xcd, smem,
                p.y[t & 3], KOP_,
                p.wif1h, p.wif1l, p.bif1, p.S1[t & 1]);
        }
    } else {                               // x(s+1) convert
        int tn = s + 1;
        if (tn < T_) {
            int c = xcd * 4 + (k - 126);
            for (int i = c * 256 + tid; i < B_ * IN_; i += 32 * 256) {
                int b = i >> 9, j = i & 511;
                float v = p.x[((size_t)b * T_ + tn) * IN_ + j];
                p.a10[tn & 3][(size_t)b * K2P_ + j] = (__bf16)v;
            }
        }
    }
}

// ---------------------------------------------------------------------------
// Setup kernels
// ---------------------------------------------------------------------------
struct ConvArgs { const float* s1; const float* s2; __bf16* dst; int s1s, K1, K2, Kd; };
struct ConvArgs4 { ConvArgs a[4]; };

__global__ __launch_bounds__(256) void conv_lstm(ConvArgs4 ca)
{
    ConvArgs c = ca.a[blockIdx.z];
    int k = blockIdx.x * 256 + threadIdx.x;
    if (k >= c.Kd) return;
    int n = blockIdx.y;
    float v = 0.f;
    if (k < c.K1) v = c.s1[(size_t)n * c.s1s + k];
    else if (k < c.K1 + c.K2) v = c.s2[(size_t)n * c.K2 + (k - c.K1)];
    c.dst[(size_t)n * c.Kd + k] = (__bf16)v;
}

__global__ __launch_bounds__(256) void conv_hi(
    const float* __restrict__ s1, int K1, const float* __restrict__ s2, int K2,
    int Nsrc, __bf16* __restrict__ hi, int Kd)
{
    int k = blockIdx.x * 256 + threadIdx.x;
    int n = blockIdx.y;
    if (k >= Kd) return;
    float v = 0.f;
    if (n < Nsrc) {
        if (k < K1) v = s1[(size_t)n * K1 + k];
        else if (k < K1 + K2) v = s2[(size_t)n * K2 + (k - K1)];
    }
    hi[(size_t)n * Kd + k] = (__bf16)v;
}

__global__ __launch_bounds__(256) void conv_hl(
    const float* __restrict__ src, int Nsrc, int K,
    __bf16* __restrict__ hi, __bf16* __restrict__ lo)
{
    int k = blockIdx.x * 256 + threadIdx.x;
    int n = blockIdx.y;
    if (k >= K) return;
    float v = (n < Nsrc) ? src[(size_t)n * K + k] : 0.f;
    split2(v, &hi[(size_t)n * K + k], &lo[(size_t)n * K + k]);
}

__global__ __launch_bounds__(256) void build_inp(const float* __restrict__ x,
                                                 __bf16* __restrict__ a1)
{
    int idx = blockIdx.x * 256 + threadIdx.x;
    if (idx >= B_ * IN_) return;
    int b = idx >> 9, j = idx & 511;
    float v = x[(size_t)b * T_ * IN_ + j];
    a1[(size_t)b * K2P_ + j] = (__bf16)v;
}

// ---------------------------------------------------------------------------
extern "C" void kernel_launch(void* const* d_in, const int* in_sizes, int n_in,
                              void* d_out, int out_size, void* d_ws, size_t ws_size,
                              hipStream_t stream)
{
    const float* x       = (const float*)d_in[0];
    const float* W_ih0   = (const float*)d_in[1];
    const float* W_hh0   = (const float*)d_in[2];
    const float* b_ih0   = (const float*)d_in[3];
    const float* b_hh0   = (const float*)d_in[4];
    const float* W_ih1   = (const float*)d_in[5];
    const float* W_hh1   = (const float*)d_in[6];
    const float* b_ih1   = (const float*)d_in[7];
    const float* b_hh1   = (const float*)d_in[8];
    const float* W_iface = (const float*)d_in[9];
    const float* b_iface = (const float*)d_in[10];
    const float* W_out   = (const float*)d_in[11];
    const float* b_out   = (const float*)d_in[12];

    P p;
    p.x = x;
    p.bih0 = b_ih0; p.bhh0 = b_hh0; p.bih1 = b_ih1; p.bhh1 = b_hh1;
    p.bif0 = b_iface; p.bif1 = b_iface + IFACE_;
    p.bout = b_out;
    p.out = (float*)d_out;

    char* ptr = (char*)d_ws;
    auto alloc = [&](size_t bytes) { char* r = ptr; ptr += (bytes + 255) & ~(size_t)255; return r; };

    // ---- zero zone (memset each call) ----
    char* zstart = ptr;
    for (int q = 0; q < 4; ++q) p.a10[q] = (__bf16*)alloc(B_ * K2P_ * 2);
    for (int q = 0; q < 4; ++q) p.a11[q] = (__bf16*)alloc(B_ * K1P_ * 2);
    for (int q = 0; q < 4; ++q) p.a20[q] = (__bf16*)alloc(B_ * K2P_ * 2);
    for (int q = 0; q < 4; ++q) p.a21[q] = (__bf16*)alloc(B_ * K2P_ * 2);
    for (int q = 0; q < 4; ++q) p.y[q]   = (__bf16*)alloc(B_ * KOP_ * 2);
    p.c00 = (float*)alloc((size_t)B_ * H_ * 4);
    p.c01 = (float*)alloc((size_t)B_ * H_ * 4);
    p.c10 = (float*)alloc((size_t)B_ * H_ * 4);
    p.c11 = (float*)alloc((size_t)B_ * H_ * 4);
    p.mem0  = (float*)alloc((size_t)B_ * M_ * WC_ * 4);
    p.link0 = (float*)alloc((size_t)B_ * M_ * M_ * 4);
    p.prec0 = (float*)alloc((size_t)B_ * M_ * 4);
    p.rw0   = (float*)alloc((size_t)B_ * R_ * M_ * 4);
    p.ww0   = (float*)alloc((size_t)B_ * M_ * 4);
    p.us0   = (float*)alloc((size_t)B_ * M_ * 4);
    p.mem1  = (float*)alloc((size_t)B_ * M_ * WC_ * 4);
    p.link1 = (float*)alloc((size_t)B_ * M_ * M_ * 4);
    p.prec1 = (float*)alloc((size_t)B_ * M_ * 4);
    p.rw1   = (float*)alloc((size_t)B_ * R_ * M_ * 4);
    p.ww1   = (float*)alloc((size_t)B_ * M_ * 4);
    p.us1   = (float*)alloc((size_t)B_ * M_ * 4);
    size_t zbytes = (size_t)(ptr - zstart);

    // ---- weights (rewritten every call) ----
    p.w10 = (__bf16*)alloc(2048ull * K2P_ * 2);
    p.w11 = (__bf16*)alloc(2048ull * K1P_ * 2);
    p.w20 = (__bf16*)alloc(2048ull * K2P_ * 2);
    p.w21 = (__bf16*)alloc(2048ull * K2P_ * 2);
    p.wo  = (__bf16*)alloc(512ull * KOP_ * 2);
    p.wif0h = (__bf16*)alloc((size_t)IFP_ * 512 * 2);
    p.wif0l = (__bf16*)alloc((size_t)IFP_ * 512 * 2);
    p.wif1h = (__bf16*)alloc((size_t)IFP_ * 512 * 2);
    p.wif1l = (__bf16*)alloc((size_t)IFP_ * 512 * 2);
    for (int q = 0; q < 2; ++q) p.S0[q] = (float*)alloc((size_t)B_ * IFP_ * 4);
    for (int q = 0; q < 2; ++q) p.S1[q] = (float*)alloc((size_t)B_ * IFP_ * 4);

    hipMemsetAsync(zstart, 0, zbytes, stream);

    // w10: drop the dead last_read columns (cols 512..591 of W_ih0 multiply
    // the never-updated, always-zero last_read) -> Kd = 1024.
    ConvArgs4 ca;
    ca.a[0] = { W_ih0,                 W_hh0,              p.w10, NNIN_, 512,   H_, K2P_ };
    ca.a[1] = { W_ih0 + 2048ull*NNIN_, W_hh0 + 2048ull*H_, p.w11, NNIN_, NNIN_, H_, K1P_ };
    ca.a[2] = { W_ih1,                 W_hh1,              p.w20, H_,    H_,    H_, K2P_ };
    ca.a[3] = { W_ih1 + 2048ull*H_,    W_hh1 + 2048ull*H_, p.w21, H_,    H_,    H_, K2P_ };
    conv_lstm<<<dim3((K1P_ + 255) / 256, 2048, 4), 256, 0, stream>>>(ca);

    conv_hi<<<dim3((KOP_ + 255) / 256, 512), 256, 0, stream>>>(
        W_out, NNIN_, nullptr, 0, 512, p.wo, KOP_);
    conv_hl<<<dim3(2, IFP_), 256, 0, stream>>>(
        W_iface, IFACE_, 512, p.wif0h, p.wif0l);
    conv_hl<<<dim3(2, IFP_), 256, 0, stream>>>(
        W_iface + (size_t)IFACE_ * 512, IFACE_, 512, p.wif1h, p.wif1l);
    build_inp<<<(B_ * IN_ + 255) / 256, 256, 0, stream>>>(x, p.a10[0]);

    // 40 pipeline slots cover t=0..31 for all 9 stages
    for (int s = 0; s < T_ + 8; ++s) {
        slot_kernel<<<1040, 256, 0, stream>>>(p, s);
    }
}